// Round 11
// baseline (1169.511 us; speedup 1.0000x reference)
//
#include <hip/hip_runtime.h>
#include <hip/hip_bf16.h>
#include <stdint.h>

typedef unsigned short u16;
typedef unsigned int u32;
typedef unsigned long long u64;
typedef __bf16 bf16x8 __attribute__((ext_vector_type(8)));
typedef float f32x4 __attribute__((ext_vector_type(4)));
typedef int i32x4 __attribute__((ext_vector_type(4)));

__device__ __forceinline__ u16 f2bf(float f){
  unsigned u = __float_as_uint(f);
  u += 0x7fffu + ((u>>16)&1u);
  return (u16)(u>>16);
}
__device__ __forceinline__ float bf2f(u16 h){ return __uint_as_float((u32)h<<16); }
__device__ __forceinline__ float sigm(float x){ return 1.f/(1.f+__expf(-x)); }
__device__ __forceinline__ float tanh_fast(float x){ float e = __expf(2.f*x); return 1.f - 2.f/(e+1.f); }

// async global->LDS, 16B per lane; LDS dest = wave-uniform base + lane*16
__device__ __forceinline__ void gl_lds16(const void* g, void* l){
  __builtin_amdgcn_global_load_lds((const __attribute__((address_space(1))) void*)g,
                                   (__attribute__((address_space(3))) void*)l, 16, 0, 0);
}

// Global K-permutation pi used by the reservoir path (makes each scan lane's values
// contiguous): within each 64-block, c = cg*16+fr  ->  fr*4+cg.
// Applied consistently to: WsQ K-dim, scan LDS state, u columns (EPI11), HsB columns,
// rdB K-dim. All consumers contract over this axis -> identity transformation.

// ---------------------------------------------------------------- prep weights
__global__ __launch_bounds__(128) void prep_weights(
  const float* Wp, const float* Wv, const float* Wo, const float* Win, const float* rd,
  const float* Wq, const float* keys, const float* vals, const float* mWo,
  const float* Wr, const float* Wi, const float* Wg, const float* fWo, const float* Rw,
  const float* bp, const float* fbr, const float* fbi, const float* fbg,
  u16* WpB, u16* WvB, u16* WoB, u16* WinB, u16* rdB,
  u16* WqB, u16* keysB, u16* valsB, u16* mWoB,
  u16* WrB, u16* WiB, u16* WgB, u16* fWoB, u16* RwB,
  float* bpp, float* bpc, float* ss)
{
  int blk = blockIdx.x, t = threadIdx.x;
  if(blk==6912){ if(t<128) bpp[t] = (t<20)? bp[t] : 0.f; return; }
  if(blk==6913){
    for(int j=t; j<1024; j+=128)
      bpc[j] = (j<256)? fbr[j] : (j<512)? fbi[j-256] : fbg[j-512];
    return;
  }
  if(blk==6914){ if(t==0) ss[0]=1.f; else if(t<5) ss[t]=0.f; return; }
  const float* src = nullptr; u16* dst = nullptr; int r;
  bool perm = false;
  if(blk<128){ r=blk; dst=WpB+(size_t)r*512; if(r<20) src=Wp+(size_t)r*512; }
  else if(blk<640){ r=blk-128; dst=WvB+(size_t)r*512; src=Wv+(size_t)r*512; }
  else if(blk<1152){ r=blk-640; dst=WoB+(size_t)r*512; src=Wo+(size_t)r*512; }
  else if(blk<1664){ r=blk-1152; dst=WinB+(size_t)r*512; src=Win+(size_t)r*512; }
  else if(blk<2176){ r=blk-1664; dst=rdB+(size_t)r*512; src=rd+(size_t)r*512; perm=true; }
  else if(blk<2688){ r=blk-2176; dst=WqB+(size_t)r*512; src=Wq+(size_t)r*512; }
  else if(blk<2752){ r=blk-2688; dst=keysB+(size_t)r*512; src=keys+(size_t)r*512; }
  else if(blk<2816){ r=blk-2752; dst=valsB+(size_t)r*512; src=vals+(size_t)r*512; }
  else if(blk<3328){ r=blk-2816; dst=mWoB+(size_t)r*512; src=mWo+(size_t)r*512; }
  else if(blk<3584){ r=blk-3328; dst=WrB+(size_t)r*512; src=Wr+(size_t)r*512; }
  else if(blk<3840){ r=blk-3584; dst=WiB+(size_t)r*512; src=Wi+(size_t)r*512; }
  else if(blk<4352){ r=blk-3840; dst=WgB+(size_t)r*512; src=Wg+(size_t)r*512; }
  else if(blk<4864){ r=blk-4352; dst=fWoB+(size_t)r*512; src=fWo+(size_t)r*512; }
  else { r=blk-4864; dst=RwB+(size_t)r*512; src=Rw+(size_t)r*512; }
  if(src){
    float4 a = *(const float4*)&src[t*4];
    ushort4 o; o.x=f2bf(a.x); o.y=f2bf(a.y); o.z=f2bf(a.z); o.w=f2bf(a.w);
    if(perm){
      // pi-scatter: k=t*4+e -> (k&~63) | ((k&15)<<2) | ((k>>4)&3); stride 4 per e
      int k0 = t*4;
      int base = (k0 & ~63) | ((k0&15)<<2) | ((k0>>4)&3);
      dst[base] = o.x; dst[base+4] = o.y; dst[base+8] = o.z; dst[base+12] = o.w;
    } else {
      *(ushort4*)&dst[t*4] = o;
    }
  } else {
    ushort4 z; z.x=0; z.y=0; z.z=0; z.w=0;
    *(ushort4*)&dst[t*4] = z;
  }
}

// transpose sheaf_Rw -> RwT' [512 out-cols][2048 K] with K = z*512 + k  (K-concat layout
// for the single fused sheaf-2 GEMM)
__global__ __launch_bounds__(256) void transpose_rw(const float* __restrict__ Rw, u16* __restrict__ RwT){
  __shared__ float tl[32][33];
  int z = blockIdx.z, it = blockIdx.x, jt = blockIdx.y;
  const float* src = Rw + (size_t)z*262144;
  int r = threadIdx.x>>3, c4 = (threadIdx.x&7)*4;
  float4 v = *(const float4*)&src[(size_t)(jt*32+r)*512 + it*32 + c4];
  tl[r][c4+0]=v.x; tl[r][c4+1]=v.y; tl[r][c4+2]=v.z; tl[r][c4+3]=v.w;
  __syncthreads();
  ushort4 o;
  o.x = f2bf(tl[c4+0][r]); o.y = f2bf(tl[c4+1][r]);
  o.z = f2bf(tl[c4+2][r]); o.w = f2bf(tl[c4+3][r]);
  *(ushort4*)&RwT[(size_t)(it*32+r)*2048 + z*512 + jt*32 + c4] = o;
}

// ---------------------------------------------------------------- layernorm -> bf16
__global__ __launch_bounds__(64) void ln_kernel(const float* __restrict__ x, const float* __restrict__ g,
      const float* __restrict__ b, u16* __restrict__ out)
{
  int row = blockIdx.x, lane = threadIdx.x;
  const float* xr = x + (size_t)row*512;
  float4 v0 = *(const float4*)&xr[lane*4];
  float4 v1 = *(const float4*)&xr[256+lane*4];
  float s = v0.x+v0.y+v0.z+v0.w + v1.x+v1.y+v1.z+v1.w;
  float q = v0.x*v0.x+v0.y*v0.y+v0.z*v0.z+v0.w*v0.w + v1.x*v1.x+v1.y*v1.y+v1.z*v1.z+v1.w*v1.w;
  #pragma unroll
  for(int m=1;m<64;m<<=1){ s += __shfl_xor(s,m); q += __shfl_xor(q,m); }
  float mean = s*(1.f/512.f);
  float var  = q*(1.f/512.f) - mean*mean;
  float rstd = rsqrtf(var + 1e-5f);
  float4 g0 = *(const float4*)&g[lane*4], g1 = *(const float4*)&g[256+lane*4];
  float4 b0 = *(const float4*)&b[lane*4], b1 = *(const float4*)&b[256+lane*4];
  ushort4 o0, o1;
  o0.x = f2bf((v0.x-mean)*rstd*g0.x + b0.x); o0.y = f2bf((v0.y-mean)*rstd*g0.y + b0.y);
  o0.z = f2bf((v0.z-mean)*rstd*g0.z + b0.z); o0.w = f2bf((v0.w-mean)*rstd*g0.w + b0.w);
  o1.x = f2bf((v1.x-mean)*rstd*g1.x + b1.x); o1.y = f2bf((v1.y-mean)*rstd*g1.y + b1.y);
  o1.z = f2bf((v1.z-mean)*rstd*g1.z + b1.z); o1.w = f2bf((v1.w-mean)*rstd*g1.w + b1.w);
  *(ushort4*)&out[(size_t)row*512 + lane*4] = o0;
  *(ushort4*)&out[(size_t)row*512 + 256 + lane*4] = o1;
}

// ---------------------------------------------------------------- generic NT GEMM (bf16 -> f32), M=4096
// BM=128, BN=64 tiles. T3-minimum double-buffered pipeline: stage(next tile, async
// global_load_lds) BEFORE compute(cur), one counted drain {vmcnt(0); s_barrier} per tile
// (loads have the whole MFMA phase to land). LDS 48KB -> still 2 blocks/CU.
// EPI: 0 none,1 +resid,4 bf16 out,5 bias+resid,6 bias+resid -> outf2(d_out)+outb(bf16),
//      8 outf -= |scal|*v, 9 ffn fused (Wr|Wi|Wg), 10 attn fused (Wp|Wv),
//     11 pi-permuted f32 store (reservoir u), 12 sheaf1: v+bias-shift_idx(x4b) -> T[r*2048+gc]
template<int EPI>
__global__ __launch_bounds__(256,2) void gemm_nt(
  const u16* __restrict__ A, const u16* __restrict__ Bw, int K, int ldc,
  float* __restrict__ outf, u16* __restrict__ outb,
  const float* __restrict__ bias, const float* __restrict__ resid,
  const float* __restrict__ aux, float* __restrict__ outf2,
  const float* __restrict__ scal, int shift_ad)
{
  __shared__ u16 Al[2][128*64];
  __shared__ u16 Bl[2][64*64];
  const int t = threadIdx.x;
  const int bm = blockIdx.x, bn = blockIdx.y;
  const int wid = t>>6, lane = t&63;
  const int wr = wid>>1, wc = wid&1;
  const int fr = lane&15, fq = lane>>4;
  f32x4 acc[4][2] = {};
  const int nK = K>>6;
  const u16* Ab = A + (size_t)(bm*128)*K;
  const u16* Bb = Bw + (size_t)(bn*64)*K;
  const int srow8 = t>>3;            // 0..31
  const int scol = (t&7)*8;          // u16 col
  char* AlB = (char*)Al; char* BlB = (char*)Bl;
  const int lbase = wid*1024;        // wave-uniform LDS byte base within each 4KB round
  // prologue: stage tile 0 -> buf 0, drain, barrier
  #pragma unroll
  for(int c=0;c<4;++c)
    gl_lds16(&Ab[(size_t)(c*32+srow8)*K + scol], AlB + c*4096 + lbase);
  #pragma unroll
  for(int c=0;c<2;++c)
    gl_lds16(&Bb[(size_t)(c*32+srow8)*K + scol], BlB + c*4096 + lbase);
  asm volatile("s_waitcnt vmcnt(0)" ::: "memory");
  __builtin_amdgcn_s_barrier();
  asm volatile("" ::: "memory");
  for(int bk=0; bk<nK; ++bk){
    const int cur = bk&1, nxt = cur^1;
    // issue next tile's async loads (land during this tile's compute)
    if(bk+1 < nK){
      #pragma unroll
      for(int c=0;c<4;++c)
        gl_lds16(&Ab[(size_t)(c*32+srow8)*K + (bk+1)*64 + scol], AlB + nxt*16384 + c*4096 + lbase);
      #pragma unroll
      for(int c=0;c<2;++c)
        gl_lds16(&Bb[(size_t)(c*32+srow8)*K + (bk+1)*64 + scol], BlB + nxt*8192 + c*4096 + lbase);
    }
    const u16* Ac = Al[cur];
    const u16* Bc = Bl[cur];
    #pragma unroll
    for(int kk=0;kk<2;++kk){
      bf16x8 af[4], bf[2];
      #pragma unroll
      for(int m=0;m<4;++m) af[m] = *(const bf16x8*)&Ac[(wr*64+m*16+fr)*64 + kk*32 + fq*8];
      #pragma unroll
      for(int n=0;n<2;++n) bf[n] = *(const bf16x8*)&Bc[(wc*32+n*16+fr)*64 + kk*32 + fq*8];
      #pragma unroll
      for(int m=0;m<4;++m)
        #pragma unroll
        for(int n=0;n<2;++n)
          acc[m][n] = __builtin_amdgcn_mfma_f32_16x16x32_bf16(af[m], bf[n], acc[m][n], 0,0,0);
    }
    // next-tile loads drained; everyone's cur-tile ds_reads done -> safe to swap
    asm volatile("s_waitcnt vmcnt(0)" ::: "memory");
    __builtin_amdgcn_s_barrier();
    asm volatile("" ::: "memory");
  }
  float alpha = 0.f;
  if(EPI==8) alpha = fabsf(scal[0]);
  #pragma unroll
  for(int m=0;m<4;++m){
    int gr0 = bm*128 + wr*64 + m*16 + fq*4;
    #pragma unroll
    for(int n=0;n<2;++n){
      int gc = bn*64 + wc*32 + n*16 + fr;
      float bv = 0.f;
      if(EPI==5||EPI==6||EPI==9||EPI==12) bv = bias[gc];
      if(EPI==10 && gc<128) bv = bias[gc];
      #pragma unroll
      for(int i=0;i<4;++i){
        int r = gr0 + i;
        float v = acc[m][n][i] + bv;
        if(EPI==1||EPI==5||EPI==6) v += resid[(size_t)r*ldc + gc];
        if(EPI==8){
          outf[(size_t)r*ldc + gc] -= alpha*v;
        } else if(EPI==9){
          if(gc<512) outf[(size_t)r*512 + gc] = v;
          else       outf2[(size_t)r*512 + gc-512] = sigm(v);
        } else if(EPI==10){
          if(gc<128) outf[(size_t)r*128 + gc] = sigm(v);
          else       outf2[(size_t)r*512 + gc-128] = v;
        } else if(EPI==11){
          int pc = (gc & ~63) | ((gc&15)<<2) | ((gc>>4)&3);
          outf[(size_t)r*512 + pc] = v;
        } else if(EPI==12){
          int idx = gc>>9;
          int ad = 3 - idx;
          int ts = r & 1023;
          float xnb = 0.f;
          if(ts >= ad) xnb = bf2f(((const u16*)aux)[(size_t)(r-ad)*512 + (gc&511)]);
          outb[(size_t)r*2048 + gc] = f2bf(v - xnb);
        } else {
          if(EPI==0||EPI==1||EPI==5) outf[(size_t)r*ldc + gc] = v;
          if(EPI==6) outf2[(size_t)r*ldc + gc] = v;
          if(EPI==4||EPI==6) outb[(size_t)r*ldc + gc] = f2bf(v);
        }
      }
    }
  }
}

// ---------------------------------------------------------------- path attention (flash style)
__global__ __launch_bounds__(128) void attn_kernel(
  const float* __restrict__ paths, const float* __restrict__ Vbuf, u16* __restrict__ ctxb)
{
  const int t = threadIdx.x;
  const int qt = blockIdx.x, bh = blockIdx.y;
  const int b = bh>>2, h = bh&3;
  const int rb = b<<10;
  const int ql = t>>2, sub = t&3;
  const int q = qt*32 + ql;
  const int wid = t>>6, lane = t&63;
  const int fr = lane&15, fq = lane>>4;
  __shared__ u16 Vl[128][72];
  __shared__ u16 Pl[32][72];
  __shared__ float pkl[64][6];
  __shared__ float scl[32];
  __shared__ float lsm[32];
  float al[5], bl[5];
  #pragma unroll
  for(int l=0;l<5;++l){
    float p = paths[(size_t)(rb+q)*128 + h*5 + l];
    al[l] = 2.f*p - 1.f; bl[l] = 1.f - p;
  }
  float m_run = -1e30f, l_run = 0.f;
  f32x4 acc[2][4] = {};
  const int nkt = (qt>>1) + 1;
  for(int kt=0; kt<nkt; ++kt){
    int k0 = kt*64;
    for(int i=t; i<320; i+=128){
      int k = i/5, l = i%5;
      pkl[k][l] = paths[(size_t)(rb+k0+k)*128 + h*5 + l];
    }
    {
      int dg = (t&31)*4, kbase = t>>5;
      #pragma unroll
      for(int i=0;i<16;++i){
        int k = kbase + i*4;
        float4 v4 = *(const float4*)&Vbuf[(size_t)(rb+k0+k)*512 + h*128 + dg];
        Vl[dg+0][k] = f2bf(v4.x); Vl[dg+1][k] = f2bf(v4.y);
        Vl[dg+2][k] = f2bf(v4.z); Vl[dg+3][k] = f2bf(v4.w);
      }
    }
    __syncthreads();
    float pj[16]; float tm = -1e30f;
    #pragma unroll
    for(int j=0;j<16;++j){
      int kidx = sub*16 + j;
      int k = k0 + kidx;
      float s;
      if(k <= q){
        float c = al[0]*pkl[kidx][0] + bl[0];
        float sa = c;
        #pragma unroll
        for(int l=1;l<5;++l){ c *= al[l]*pkl[kidx][l] + bl[l]; sa += c; }
        s = sa*0.2f;
      } else s = -1e30f;
      pj[j] = s; tm = fmaxf(tm, s);
    }
    tm = fmaxf(tm, __shfl_xor(tm,1,4));
    tm = fmaxf(tm, __shfl_xor(tm,2,4));
    float m_new = fmaxf(m_run, tm);
    float corr = __expf(m_run - m_new);
    float ls = 0.f;
    #pragma unroll
    for(int j=0;j<16;++j){
      float p = (pj[j] > -1e29f) ? __expf(pj[j]-m_new) : 0.f;
      ls += p;
      Pl[ql][sub*16+j] = f2bf(p);
    }
    l_run = l_run*corr + ls;
    m_run = m_new;
    if(sub==0) scl[ql] = corr;
    __syncthreads();
    #pragma unroll
    for(int m=0;m<2;++m){
      float c0 = scl[m*16+fq*4+0], c1 = scl[m*16+fq*4+1];
      float c2 = scl[m*16+fq*4+2], c3 = scl[m*16+fq*4+3];
      #pragma unroll
      for(int n=0;n<4;++n){ acc[m][n][0]*=c0; acc[m][n][1]*=c1; acc[m][n][2]*=c2; acc[m][n][3]*=c3; }
    }
    #pragma unroll
    for(int kk=0;kk<2;++kk){
      bf16x8 af[2], bf[4];
      #pragma unroll
      for(int m=0;m<2;++m) af[m] = *(const bf16x8*)&Pl[m*16+fr][kk*32+fq*8];
      #pragma unroll
      for(int n=0;n<4;++n) bf[n] = *(const bf16x8*)&Vl[wid*64+n*16+fr][kk*32+fq*8];
      #pragma unroll
      for(int m=0;m<2;++m)
        #pragma unroll
        for(int n=0;n<4;++n)
          acc[m][n] = __builtin_amdgcn_mfma_f32_16x16x32_bf16(af[m], bf[n], acc[m][n], 0,0,0);
    }
    __syncthreads();
  }
  {
    float lt = l_run + __shfl_xor(l_run,1,4);
    lt += __shfl_xor(lt,2,4);
    if(sub==0) lsm[ql] = lt;
  }
  __syncthreads();
  #pragma unroll
  for(int m=0;m<2;++m){
    float inv[4];
    #pragma unroll
    for(int i=0;i<4;++i) inv[i] = 1.f/lsm[m*16+fq*4+i];
    #pragma unroll
    for(int n=0;n<4;++n){
      int row = rb + qt*32 + m*16 + fq*4;
      int col = h*128 + wid*64 + n*16 + fr;
      #pragma unroll
      for(int i=0;i<4;++i)
        ctxb[(size_t)(row+i)*512 + col] = f2bf(acc[m][n][i]*inv[i]);
    }
  }
}

// ---------------------------------------------------------------- power-iteration matvec
__global__ __launch_bounds__(256) void pmv(const float* __restrict__ W, const float* __restrict__ vin,
                    const float* __restrict__ ssin, float* __restrict__ vout, float* __restrict__ ssout)
{
  __shared__ float vs[512];
  int t = threadIdx.x;
  int j = blockIdx.x*16 + (t>>4), ks = t&15;
  float s = ssin[0];
  float inv = (s>0.f)? rsqrtf(s) : 1.f;
  vs[t] = vin[t]*inv; vs[t+256] = vin[t+256]*inv;
  __syncthreads();
  float p = 0.f;
  const float* wr = &W[(size_t)j*512 + ks*32];
  #pragma unroll
  for(int kk=0;kk<32;++kk) p += wr[kk]*vs[ks*32+kk];
  p += __shfl_xor(p,1,16); p += __shfl_xor(p,2,16); p += __shfl_xor(p,4,16); p += __shfl_xor(p,8,16);
  if(ks==0){ vout[j] = p; atomicAdd(ssout, p*p); }
}

// scale + i8-quantize Ws rows (per-row scale), K stored in pi-order.
__global__ __launch_bounds__(128) void scale_ws(const float* __restrict__ Wres, const float* __restrict__ ss4,
                         const float* __restrict__ logrho, signed char* __restrict__ WsQ,
                         float* __restrict__ wscale)
{
  __shared__ float wmax[2];
  int j = blockIdx.x, t = threadIdx.x;
  int fr = t&15, blk = t>>4;
  float rho_t = 1.5f * sigm(logrho[0]);
  float rho_c = sqrtf(ss4[0]);
  float sc = rho_t / fmaxf(rho_c, 1e-6f);
  float w[4];
  #pragma unroll
  for(int cg=0;cg<4;++cg) w[cg] = Wres[(size_t)j*512 + blk*64 + cg*16 + fr]*sc;
  float m = fmaxf(fmaxf(fabsf(w[0]),fabsf(w[1])), fmaxf(fabsf(w[2]),fabsf(w[3])));
  #pragma unroll
  for(int d=1; d<64; d<<=1) m = fmaxf(m, __shfl_xor(m, d));
  if((t&63)==0) wmax[t>>6] = m;
  __syncthreads();
  float rm = fmaxf(wmax[0], wmax[1]);
  float qs = (rm > 0.f) ? rm*(1.f/127.f) : 1.f;
  float inv = 1.f/qs;
  int q0 = __float2int_rn(w[0]*inv), q1 = __float2int_rn(w[1]*inv);
  int q2 = __float2int_rn(w[2]*inv), q3 = __float2int_rn(w[3]*inv);
  q0 = min(127,max(-127,q0)); q1 = min(127,max(-127,q1));
  q2 = min(127,max(-127,q2)); q3 = min(127,max(-127,q3));
  u32 pk = (u32)(q0&0xff) | ((u32)(q1&0xff)<<8) | ((u32)(q2&0xff)<<16) | ((u32)(q3&0xff)<<24);
  *(u32*)&WsQ[(size_t)j*512 + blk*64 + fr*4] = pk;
  if(t==0) wscale[j] = qs*(1.f/127.f);
}

// ---------------------------------------------------------------- reservoir scan: SINGLE workgroup
// 1024 threads = 16 waves (4 waves/SIMD), r8/r10 barrier skeleton. Each lane owns
// (batch fq, 2 pi-contiguous cols). HsB history store DEFERRED to the next iteration's
// top (off the pre-barrier critical path; only the 2B state ds_write gates the barrier).
// Ws register/AGPR-resident i8 MFMA B-fragments (asm-pinned). 16-row zero-padded state
// tile, XOR bank-swizzle on reads, matching XOR on writes.
__global__ __launch_bounds__(1024) void scan_kernel(
  const signed char* __restrict__ WsQ, const float* __restrict__ wscale,
  const float* __restrict__ u, const float* __restrict__ leak_p,
  u16* __restrict__ HsB)
{
  const int t = threadIdx.x;
  const int w = t>>6, lane = t&63, fr = lane&15, fq = lane>>4;
  const float lk = sigm(leak_p[0]);
  const float omlk = 1.f - lk;
  __shared__ signed char Sl[2][16*512];        // [parity][16 rows][512] i8; rows !=4b stay 0
  for(int i=t; i<4096; i+=1024) ((u32*)Sl)[i] = 0u;
  // lane owns batch fq, pi-positions pc = w*32 + fr*2 + {0,1}
  const int pbase = w*32 + fr*2;
  float mysc[2];
  i32x4 bw[2][8];
  #pragma unroll
  for(int cg=0; cg<2; ++cg){
    int pc = pbase + cg;
    int oc = (pc & ~63) | ((pc&3)<<4) | ((pc>>2)&15);   // inverse-pi: orig col
    mysc[cg] = wscale[oc];
    #pragma unroll
    for(int ks=0; ks<8; ++ks)
      bw[cg][ks] = *(const i32x4*)&WsQ[(size_t)oc*512 + ks*64 + fq*16];
  }
  #pragma unroll
  for(int cg=0; cg<2; ++cg)
    #pragma unroll
    for(int ks=0; ks<8; ++ks)
      asm volatile("" : "+v"(bw[cg][ks]));
  float hp0 = 0.f, hp1 = 0.f;
  const float* up = u + (size_t)(fq*1024)*512 + pbase;   // pi-ordered u
  u16* hsp = HsB + (size_t)(fq*1024)*512 + pbase;        // pi-ordered Hs
  float2 uvc = *(const float2*)up;  up += 512;
  const int rdswz = ((fr&3)<<4) ^ (((fr>>2)&3)<<6);   // read-side bank swizzle for row fr
  const int woff = (4*fq)*512 + (pbase ^ (fq<<6));    // write slot (row 4fq), b16
  u32 p01v = 0u;                                      // deferred history word
  __syncthreads();
  for(int ts=0; ts<1024; ++ts){
    // prefetch next step's u (ts=1023 overreads one row into ws scratch - safe, unused)
    float2 uvn = *(const float2*)up;  up += 512;
    // deferred history store from previous step (fire-and-forget, off critical path)
    if(ts > 0){ *(u32*)hsp = p01v;  hsp += 512; }
    const signed char* Sb = Sl[ts&1];
    i32x4 accA[2], accB[2];
    { i32x4 z = {0,0,0,0}; accA[0]=z; accA[1]=z; accB[0]=z; accB[1]=z; }
    {
      i32x4 af[4];
      #pragma unroll
      for(int ks=0; ks<4; ++ks)
        af[ks] = *(const i32x4*)&Sb[fr*512 + ((ks*64 + fq*16) ^ rdswz)];
      #pragma unroll
      for(int ks=0; ks<4; ++ks){
        accA[0] = __builtin_amdgcn_mfma_i32_16x16x64_i8(af[ks], bw[0][ks], accA[0], 0,0,0);
        accA[1] = __builtin_amdgcn_mfma_i32_16x16x64_i8(af[ks], bw[1][ks], accA[1], 0,0,0);
      }
    }
    {
      i32x4 af[4];
      #pragma unroll
      for(int ks=0; ks<4; ++ks)
        af[ks] = *(const i32x4*)&Sb[fr*512 + (((ks+4)*64 + fq*16) ^ rdswz)];
      #pragma unroll
      for(int ks=0; ks<4; ++ks){
        accB[0] = __builtin_amdgcn_mfma_i32_16x16x64_i8(af[ks], bw[0][ks+4], accB[0], 0,0,0);
        accB[1] = __builtin_amdgcn_mfma_i32_16x16x64_i8(af[ks], bw[1][ks+4], accB[1], 0,0,0);
      }
    }
    // epilogue: batch fq, 2 pi-contiguous cols
    float pre0 = (float)(accA[0][0] + accB[0][0])*mysc[0] + uvc.x;
    float pre1 = (float)(accA[1][0] + accB[1][0])*mysc[1] + uvc.y;
    float h0 = omlk*hp0 + lk*tanh_fast(pre0);
    float h1 = omlk*hp1 + lk*tanh_fast(pre1);
    hp0 = h0; hp1 = h1;
    // i8 state publish FIRST (the only thing gating the barrier); no clamp (|h|<=1)
    int q0 = __float2int_rn(h0*127.f), q1 = __float2int_rn(h1*127.f);
    u16 qp = (u16)((q0&0xff) | ((q1&0xff)<<8));
    *(u16*)&Sl[(ts+1)&1][woff] = qp;
    // pack history for deferred store next iteration
    asm volatile("v_cvt_pk_bf16_f32 %0, %1, %2" : "=v"(p01v) : "v"(h0), "v"(h1));
    uvc = uvn;
    // LDS-only visibility barrier: wait DS ops, NOT in-flight global stores/loads
    asm volatile("s_waitcnt lgkmcnt(0)" ::: "memory");
    __builtin_amdgcn_s_barrier();
    asm volatile("" ::: "memory");
  }
  *(u32*)hsp = p01v;   // final step's history
}

// ---------------------------------------------------------------- memory attention (M=64 keys)
__global__ __launch_bounds__(256) void mem_kernel(
  const u16* __restrict__ qb, const u16* __restrict__ keysB, const u16* __restrict__ valsB,
  u16* __restrict__ ctx2b)
{
  const int t = threadIdx.x, rt = blockIdx.x;
  const int wid = t>>6, lane = t&63, fr = lane&15, fq = lane>>4;
  __shared__ float S[64][65];
  __shared__ u16 Pl[64][72];
  __shared__ u16 VT[256][72];
  {
    f32x4 accs[4] = {};
    for(int ks=0; ks<16; ++ks){
      bf16x8 bfrag = *(const bf16x8*)&keysB[(size_t)(wid*16+fr)*512 + ks*32 + fq*8];
      #pragma unroll
      for(int mt=0;mt<4;++mt){
        bf16x8 afrag = *(const bf16x8*)&qb[(size_t)(rt*64+mt*16+fr)*512 + ks*32 + fq*8];
        accs[mt] = __builtin_amdgcn_mfma_f32_16x16x32_bf16(afrag, bfrag, accs[mt], 0,0,0);
      }
    }
    #pragma unroll
    for(int mt=0;mt<4;++mt)
      #pragma unroll
      for(int i=0;i<4;++i)
        S[mt*16+fq*4+i][wid*16+fr] = accs[mt][i];
  }
  __syncthreads();
  if(t<64){
    float m = -1e30f;
    for(int j=0;j<64;++j) m = fmaxf(m, S[t][j]);
    const float scale = 0.04419417382f; // 1/sqrt(512)
    float sum = 0.f;
    for(int j=0;j<64;++j){ float p = __expf((S[t][j]-m)*scale); sum += p; S[t][j] = p; }
    float inv = 1.f/sum;
    for(int j=0;j<64;++j) Pl[t][j] = f2bf(S[t][j]*inv);
  }
  __syncthreads();
  for(int pass=0; pass<2; ++pass){
    {
      int k = t&63, cb = t>>6;
      #pragma unroll
      for(int i=0;i<8;++i){
        int d0 = (cb + i*4)*8;
        uint4 v = *(const uint4*)&valsB[(size_t)k*512 + pass*256 + d0];
        VT[d0+0][k]=(u16)(v.x); VT[d0+1][k]=(u16)(v.x>>16);
        VT[d0+2][k]=(u16)(v.y); VT[d0+3][k]=(u16)(v.y>>16);
        VT[d0+4][k]=(u16)(v.z); VT[d0+5][k]=(u16)(v.z>>16);
        VT[d0+6][k]=(u16)(v.w); VT[d0+7][k]=(u16)(v.w>>16);
      }
    }
    __syncthreads();
    f32x4 accp[4][4] = {};
    #pragma unroll
    for(int kk=0;kk<2;++kk){
      bf16x8 af[4], bf[4];
      #pragma unroll
      for(int mt=0;mt<4;++mt) af[mt] = *(const bf16x8*)&Pl[mt*16+fr][kk*32+fq*8];
      #pragma unroll
      for(int nt=0;nt<4;++nt) bf[nt] = *(const bf16x8*)&VT[wid*64+nt*16+fr][kk*32+fq*8];
      #pragma unroll
      for(int mt=0;mt<4;++mt)
        #pragma unroll
        for(int nt=0;nt<4;++nt)
          accp[mt][nt] = __builtin_amdgcn_mfma_f32_16x16x32_bf16(af[mt], bf[nt], accp[mt][nt], 0,0,0);
    }
    #pragma unroll
    for(int mt=0;mt<4;++mt)
      #pragma unroll
      for(int nt=0;nt<4;++nt){
        int row = rt*64 + mt*16 + fq*4;
        int col = pass*256 + wid*64 + nt*16 + fr;
        #pragma unroll
        for(int i=0;i<4;++i)
          ctx2b[(size_t)(row+i)*512 + col] = f2bf(accp[mt][nt][i]);
      }
    __syncthreads();
  }
}

// ---------------------------------------------------------------- ffn prod*gate -> bf16
__global__ __launch_bounds__(256) void prodgate(const float* __restrict__ ri, const float* __restrict__ g,
                         u16* __restrict__ pgb)
{
  int gi = blockIdx.x*256 + threadIdx.x;
  int row = gi>>7, c4 = (gi&127)*4;
  const float* base = ri + (size_t)row*512;
  float4 gv = *(const float4*)&g[(size_t)row*512 + c4];
  float4 o;
  if(c4 < 256){
    float4 r = *(const float4*)&base[c4];
    float4 ii = *(const float4*)&base[256+c4];
    o.x = (r.x*r.x - ii.x*ii.x)*gv.x; o.y = (r.y*r.y - ii.y*ii.y)*gv.y;
    o.z = (r.z*r.z - ii.z*ii.z)*gv.z; o.w = (r.w*r.w - ii.w*ii.w)*gv.w;
  } else {
    float4 r = *(const float4*)&base[c4-256];
    float4 ii = *(const float4*)&base[c4];
    o.x = 2.f*r.x*ii.x*gv.x; o.y = 2.f*r.y*ii.y*gv.y;
    o.z = 2.f*r.z*ii.z*gv.z; o.w = 2.f*r.w*ii.w*gv.w;
  }
  ushort4 us; us.x=f2bf(o.x); us.y=f2bf(o.y); us.z=f2bf(o.z); us.w=f2bf(o.w);
  *(ushort4*)&pgb[(size_t)row*512 + c4] = us;
}

// ================================================================ host
static void launch_gemm(int epi, dim3 grid, const u16* A, const u16* B, int K, int ldc,
  float* outf, u16* outb, const float* bias, const float* resid, const float* aux,
  float* outf2, const float* scal, int ad, hipStream_t s)
{
  switch(epi){
    case 0: gemm_nt<0><<<grid,256,0,s>>>(A,B,K,ldc,outf,outb,bias,resid,aux,outf2,scal,ad); break;
    case 1: gemm_nt<1><<<grid,256,0,s>>>(A,B,K,ldc,outf,outb,bias,resid,aux,outf2,scal,ad); break;
    case 4: gemm_nt<4><<<grid,256,0,s>>>(A,B,K,ldc,outf,outb,bias,resid,aux,outf2,scal,ad); break;
    case 5: gemm_nt<5><<<grid,256,0,s>>>(A,B,K,ldc,outf,outb,bias,resid,aux,outf2,scal,ad); break;
    case 6: gemm_nt<6><<<grid,256,0,s>>>(A,B,K,ldc,outf,outb,bias,resid,aux,outf2,scal,ad); break;
    case 8: gemm_nt<8><<<grid,256,0,s>>>(A,B,K,ldc,outf,outb,bias,resid,aux,outf2,scal,ad); break;
    case 9: gemm_nt<9><<<grid,256,0,s>>>(A,B,K,ldc,outf,outb,bias,resid,aux,outf2,scal,ad); break;
    case 10: gemm_nt<10><<<grid,256,0,s>>>(A,B,K,ldc,outf,outb,bias,resid,aux,outf2,scal,ad); break;
    case 11: gemm_nt<11><<<grid,256,0,s>>>(A,B,K,ldc,outf,outb,bias,resid,aux,outf2,scal,ad); break;
    case 12: gemm_nt<12><<<grid,256,0,s>>>(A,B,K,ldc,outf,outb,bias,resid,aux,outf2,scal,ad); break;
  }
}

extern "C" void kernel_launch(void* const* d_in, const int* in_sizes, int n_in,
                              void* d_out, int out_size, void* d_ws, size_t ws_size,
                              hipStream_t stream)
{
  const float* x      = (const float*)d_in[0];
  const float* ln1g   = (const float*)d_in[1];  const float* ln1b = (const float*)d_in[2];
  const float* ln2g   = (const float*)d_in[3];  const float* ln2b = (const float*)d_in[4];
  const float* ln3g   = (const float*)d_in[5];  const float* ln3b = (const float*)d_in[6];
  const float* ln4g   = (const float*)d_in[7];  const float* ln4b = (const float*)d_in[8];
  const float* aWp    = (const float*)d_in[9];  const float* abp  = (const float*)d_in[10];
  const float* aWv    = (const float*)d_in[11]; const float* aWo  = (const float*)d_in[12];
  const float* fWr    = (const float*)d_in[13]; const float* fbr  = (const float*)d_in[14];
  const float* fWi    = (const float*)d_in[15]; const float* fbi  = (const float*)d_in[16];
  const float* fWg    = (const float*)d_in[17]; const float* fbg  = (const float*)d_in[18];
  const float* fWo    = (const float*)d_in[19]; const float* fbo  = (const float*)d_in[20];
  const float* rWin   = (const float*)d_in[21]; const float* rWres= (const float*)d_in[22];
  const float* rlogr  = (const float*)d_in[23]; const float* rleak= (const float*)d_in[24];
  const float* rread  = (const float*)d_in[25]; const float* rv0  = (const float*)d_in[26];
  const float* mkeys  = (const float*)d_in[27]; const float* mvals= (const float*)d_in[28];
  const float* mWq    = (const float*)d_in[29]; const float* mWo  = (const float*)d_in[30];
  const float* mbo    = (const float*)d_in[31];
  const float* sRw    = (const float*)d_in[32]; const float* sRb  = (const float*)d_in[33];
  const float* salpha = (const float*)d_in[34];
  (void)in_sizes; (void)n_in; (void)out_size;

  char* ws = (char*)d_ws;
  float* XCUR  = (float*)(ws + 0);               // x1..x3 running residual
  u16*   X4B   = (u16*)  (ws + 8388608);         // bf16 x4 (HB region; HB dead by then)
  u16*   HB    = (u16*)  (ws + 8388608);         // ln outputs
  float* VU    = (float*)(ws + 12582912);        // V / u(pi) / ri
  u16*   TBUF  = (u16*)  (ws + 12582912);        // sheaf T [4096][2048] bf16 = 16MB
                                                 //   (VU/PATHS/CTXB/HSB all dead at sheaf)
  float* PATHS = (float*)(ws + 20971520);
  u16*   CTXB  = (u16*)  (ws + 23068672);        // ctx / qb / pgb
  u16*   HSB   = (u16*)  (ws + 27262976);        // Hs(pi cols) / ctx2b
  char* WB = ws + 31457280;
  u16* WpB   = (u16*)(WB + 0);                   // 128 rows } contiguous 640-row block
  u16* WvB   = (u16*)(WB + 131072);              // 512 rows }
  u16* WoB   = (u16*)(WB + 655360);
  u16* WinB  = (u16*)(WB + 1179648);
  u16* rdB   = (u16*)(WB + 1703936);             // K in pi-order
  u16* WqB   = (u16*)(WB + 2228224);
  u16* keysB = (u16*)(WB + 2752512);
  u16* valsB = (u16*)(WB + 2818048);
  u16* mWoB  = (u16*)(WB + 2883584);
  u16* WrB   = (u16*)(WB + 3407872);             // 256 rows } contiguous 1024-row block
  u16* WiB   = (u16*)(WB + 3670016);             // 256 rows }
  u16* WgB   = (u16*)(WB + 3932160);             // 512 rows }
  u16* fWoB  = (u16*)(WB + 4456448);
  u16* RwB   = (u16*)(WB + 4980736);             // 2048 rows contiguous (sheaf-1 fused B)
  u16* RwTB  = (u16*)(WB + 7077888);             // RwT' [512][2048] (sheaf-2 fused B)
  signed char* WsQ = (signed char*)(WB + 9175040); // 512x512 i8, K pi-order
  float* wscale = (float*)(WB + 9437184);
  float* bpp = (float*)(WB + 9699328);             // 128 f32 (padded attn path bias)
  float* bpc = (float*)(WB + 9699840);             // 1024 f32 (ffn concat bias)
  float* ssv = (float*)(WB + 9733632);
  float* vr  = (float*)(WB + 9733696);             // 4 x 512 f32
  float* GATE = (float*)d_out;                     // gate scratch, overwritten by x4 later

  if(ws_size < (size_t)41200000) return;

  prep_weights<<<6915,128,0,stream>>>(aWp,aWv,aWo,rWin,rread,mWq,mkeys,mvals,mWo,fWr,fWi,fWg,fWo,sRw,
      abp, fbr, fbi, fbg,
      WpB,WvB,WoB,WinB,rdB,WqB,keysB,valsB,mWoB,WrB,WiB,WgB,fWoB,RwB,bpp,bpc,ssv);
  transpose_rw<<<dim3(16,16,4),256,0,stream>>>(sRw, RwTB);

  dim3 g512(32,8), g640(32,10), g1024(32,16), g2048(32,32);

  // ---- attention (Wp+Wv fused)
  ln_kernel<<<4096,64,0,stream>>>(x, ln1g, ln1b, HB);
  launch_gemm(10, g640, HB, WpB, 512, 0, PATHS, nullptr, bpp, nullptr, nullptr, VU, nullptr, 0, stream);
  attn_kernel<<<dim3(32,16),128,0,stream>>>(PATHS, VU, CTXB);
  launch_gemm(1, g512, CTXB, WoB, 512, 512, XCUR, nullptr, nullptr, x, nullptr, nullptr, nullptr, 0, stream);

  // ---- reservoir (u written in pi-order via EPI11)
  ln_kernel<<<4096,64,0,stream>>>(XCUR, ln2g, ln2b, HB);
  launch_gemm(11, g512, HB, WinB, 512, 512, VU, nullptr, nullptr, nullptr, nullptr, nullptr, nullptr, 0, stream);
  pmv<<<32,256,0,stream>>>(rWres, rv0,   &ssv[0], &vr[0],    &ssv[1]);
  pmv<<<32,256,0,stream>>>(rWres, &vr[0],   &ssv[1], &vr[512],  &ssv[2]);
  pmv<<<32,256,0,stream>>>(rWres, &vr[512], &ssv[2], &vr[1024], &ssv[3]);
  pmv<<<32,256,0,stream>>>(rWres, &vr[1024],&ssv[3], &vr[1536], &ssv[4]);
  scale_ws<<<512,128,0,stream>>>(rWres, &ssv[4], rlogr, WsQ, wscale);
  scan_kernel<<<1,1024,0,stream>>>(WsQ, wscale, VU, rleak, HSB);
  launch_gemm(1, g512, HSB, rdB, 512, 512, XCUR, nullptr, nullptr, XCUR, nullptr, nullptr, nullptr, 0, stream);

  // ---- memory
  ln_kernel<<<4096,64,0,stream>>>(XCUR, ln3g, ln3b, HB);
  launch_gemm(4, g512, HB, WqB, 512, 512, nullptr, CTXB, nullptr, nullptr, nullptr, nullptr, nullptr, 0, stream);
  mem_kernel<<<64,256,0,stream>>>(CTXB, keysB, valsB, HSB);
  launch_gemm(5, g512, HSB, mWoB, 512, 512, XCUR, nullptr, mbo, XCUR, nullptr, nullptr, nullptr, 0, stream);

  // ---- ffn (Wr+Wi+Wg fused)
  ln_kernel<<<4096,64,0,stream>>>(XCUR, ln4g, ln4b, HB);
  launch_gemm(9, g1024, HB, WrB, 512, 0, VU, nullptr, bpc, nullptr, nullptr, GATE, nullptr, 0, stream);
  prodgate<<<2048,256,0,stream>>>(VU, GATE, CTXB);
  // x4 = x3 + ffn_out -> d_out (f32) + X4B (bf16, in dead HB region)
  launch_gemm(6, g512, CTXB, fWoB, 512, 512, nullptr, X4B, fbo, XCUR, nullptr, (float*)d_out, nullptr, 0, stream);

  // ---- sheaf, 2 fused GEMMs:
  // T[r][idx*512+c] = (x4@Rw_idx^T)[r][c] + Rb[idx][c] - shift_idx(x4)[r][c]   (EPI12, bf16)
  launch_gemm(12, g2048, X4B, RwB, 512, 0, nullptr, TBUF, sRb, nullptr, (const float*)X4B, nullptr, nullptr, 0, stream);
  // d_out -= |alpha| * T @ RwT'   (K=2048 contraction == sum over idx of T_idx@Rw_idx)
  launch_gemm(8, g512, TBUF, RwTB, 2048, 512, (float*)d_out, nullptr, nullptr, nullptr, nullptr, nullptr, salpha, 0, stream);
}

// Round 12
// 1141.391 us; speedup vs baseline: 1.0246x; 1.0246x over previous
//
#include <hip/hip_runtime.h>
#include <hip/hip_bf16.h>
#include <stdint.h>

typedef unsigned short u16;
typedef unsigned int u32;
typedef unsigned long long u64;
typedef __bf16 bf16x8 __attribute__((ext_vector_type(8)));
typedef float f32x4 __attribute__((ext_vector_type(4)));
typedef int i32x4 __attribute__((ext_vector_type(4)));

__device__ __forceinline__ u16 f2bf(float f){
  unsigned u = __float_as_uint(f);
  u += 0x7fffu + ((u>>16)&1u);
  return (u16)(u>>16);
}
__device__ __forceinline__ float bf2f(u16 h){ return __uint_as_float((u32)h<<16); }
__device__ __forceinline__ float sigm(float x){ return 1.f/(1.f+__expf(-x)); }
__device__ __forceinline__ float tanh_fast(float x){ float e = __expf(2.f*x); return 1.f - 2.f/(e+1.f); }

// async global->LDS, 16B per lane; LDS dest = wave-uniform base + lane*16
__device__ __forceinline__ void gl_lds16(const void* g, void* l){
  __builtin_amdgcn_global_load_lds((const __attribute__((address_space(1))) void*)g,
                                   (__attribute__((address_space(3))) void*)l, 16, 0, 0);
}

// Global K-permutation pi used by the reservoir path (makes each scan lane's values
// contiguous): within each 64-block, c = cg*16+fr  ->  fr*4+cg.
// Applied consistently to: WsQ K-dim, scan LDS state, u columns (EPI11), HsB columns,
// rdB K-dim. All consumers contract over this axis -> identity transformation.

// ---------------------------------------------------------------- prep weights
__global__ __launch_bounds__(128) void prep_weights(
  const float* Wp, const float* Wv, const float* Wo, const float* Win, const float* rd,
  const float* Wq, const float* keys, const float* vals, const float* mWo,
  const float* Wr, const float* Wi, const float* Wg, const float* fWo, const float* Rw,
  const float* bp, const float* fbr, const float* fbi, const float* fbg,
  u16* WpB, u16* WvB, u16* WoB, u16* WinB, u16* rdB,
  u16* WqB, u16* keysB, u16* valsB, u16* mWoB,
  u16* WrB, u16* WiB, u16* WgB, u16* fWoB, u16* RwB,
  float* bpp, float* bpc, float* ss)
{
  int blk = blockIdx.x, t = threadIdx.x;
  if(blk==6912){ if(t<128) bpp[t] = (t<20)? bp[t] : 0.f; return; }
  if(blk==6913){
    for(int j=t; j<1024; j+=128)
      bpc[j] = (j<256)? fbr[j] : (j<512)? fbi[j-256] : fbg[j-512];
    return;
  }
  if(blk==6914){ if(t==0) ss[0]=1.f; else if(t<5) ss[t]=0.f; return; }
  const float* src = nullptr; u16* dst = nullptr; int r;
  bool perm = false;
  if(blk<128){ r=blk; dst=WpB+(size_t)r*512; if(r<20) src=Wp+(size_t)r*512; }
  else if(blk<640){ r=blk-128; dst=WvB+(size_t)r*512; src=Wv+(size_t)r*512; }
  else if(blk<1152){ r=blk-640; dst=WoB+(size_t)r*512; src=Wo+(size_t)r*512; }
  else if(blk<1664){ r=blk-1152; dst=WinB+(size_t)r*512; src=Win+(size_t)r*512; }
  else if(blk<2176){ r=blk-1664; dst=rdB+(size_t)r*512; src=rd+(size_t)r*512; perm=true; }
  else if(blk<2688){ r=blk-2176; dst=WqB+(size_t)r*512; src=Wq+(size_t)r*512; }
  else if(blk<2752){ r=blk-2688; dst=keysB+(size_t)r*512; src=keys+(size_t)r*512; }
  else if(blk<2816){ r=blk-2752; dst=valsB+(size_t)r*512; src=vals+(size_t)r*512; }
  else if(blk<3328){ r=blk-2816; dst=mWoB+(size_t)r*512; src=mWo+(size_t)r*512; }
  else if(blk<3584){ r=blk-3328; dst=WrB+(size_t)r*512; src=Wr+(size_t)r*512; }
  else if(blk<3840){ r=blk-3584; dst=WiB+(size_t)r*512; src=Wi+(size_t)r*512; }
  else if(blk<4352){ r=blk-3840; dst=WgB+(size_t)r*512; src=Wg+(size_t)r*512; }
  else if(blk<4864){ r=blk-4352; dst=fWoB+(size_t)r*512; src=fWo+(size_t)r*512; }
  else { r=blk-4864; dst=RwB+(size_t)r*512; src=Rw+(size_t)r*512; }
  if(src){
    float4 a = *(const float4*)&src[t*4];
    ushort4 o; o.x=f2bf(a.x); o.y=f2bf(a.y); o.z=f2bf(a.z); o.w=f2bf(a.w);
    if(perm){
      // pi-scatter: k=t*4+e -> (k&~63) | ((k&15)<<2) | ((k>>4)&3); stride 4 per e
      int k0 = t*4;
      int base = (k0 & ~63) | ((k0&15)<<2) | ((k0>>4)&3);
      dst[base] = o.x; dst[base+4] = o.y; dst[base+8] = o.z; dst[base+12] = o.w;
    } else {
      *(ushort4*)&dst[t*4] = o;
    }
  } else {
    ushort4 z; z.x=0; z.y=0; z.z=0; z.w=0;
    *(ushort4*)&dst[t*4] = z;
  }
}

// transpose sheaf_Rw -> RwT' [512 out-cols][2048 K] with K = z*512 + k  (K-concat layout
// for the single fused sheaf-2 GEMM)
__global__ __launch_bounds__(256) void transpose_rw(const float* __restrict__ Rw, u16* __restrict__ RwT){
  __shared__ float tl[32][33];
  int z = blockIdx.z, it = blockIdx.x, jt = blockIdx.y;
  const float* src = Rw + (size_t)z*262144;
  int r = threadIdx.x>>3, c4 = (threadIdx.x&7)*4;
  float4 v = *(const float4*)&src[(size_t)(jt*32+r)*512 + it*32 + c4];
  tl[r][c4+0]=v.x; tl[r][c4+1]=v.y; tl[r][c4+2]=v.z; tl[r][c4+3]=v.w;
  __syncthreads();
  ushort4 o;
  o.x = f2bf(tl[c4+0][r]); o.y = f2bf(tl[c4+1][r]);
  o.z = f2bf(tl[c4+2][r]); o.w = f2bf(tl[c4+3][r]);
  *(ushort4*)&RwT[(size_t)(it*32+r)*2048 + z*512 + jt*32 + c4] = o;
}

// ---------------------------------------------------------------- layernorm -> bf16
__global__ __launch_bounds__(64) void ln_kernel(const float* __restrict__ x, const float* __restrict__ g,
      const float* __restrict__ b, u16* __restrict__ out)
{
  int row = blockIdx.x, lane = threadIdx.x;
  const float* xr = x + (size_t)row*512;
  float4 v0 = *(const float4*)&xr[lane*4];
  float4 v1 = *(const float4*)&xr[256+lane*4];
  float s = v0.x+v0.y+v0.z+v0.w + v1.x+v1.y+v1.z+v1.w;
  float q = v0.x*v0.x+v0.y*v0.y+v0.z*v0.z+v0.w*v0.w + v1.x*v1.x+v1.y*v1.y+v1.z*v1.z+v1.w*v1.w;
  #pragma unroll
  for(int m=1;m<64;m<<=1){ s += __shfl_xor(s,m); q += __shfl_xor(q,m); }
  float mean = s*(1.f/512.f);
  float var  = q*(1.f/512.f) - mean*mean;
  float rstd = rsqrtf(var + 1e-5f);
  float4 g0 = *(const float4*)&g[lane*4], g1 = *(const float4*)&g[256+lane*4];
  float4 b0 = *(const float4*)&b[lane*4], b1 = *(const float4*)&b[256+lane*4];
  ushort4 o0, o1;
  o0.x = f2bf((v0.x-mean)*rstd*g0.x + b0.x); o0.y = f2bf((v0.y-mean)*rstd*g0.y + b0.y);
  o0.z = f2bf((v0.z-mean)*rstd*g0.z + b0.z); o0.w = f2bf((v0.w-mean)*rstd*g0.w + b0.w);
  o1.x = f2bf((v1.x-mean)*rstd*g1.x + b1.x); o1.y = f2bf((v1.y-mean)*rstd*g1.y + b1.y);
  o1.z = f2bf((v1.z-mean)*rstd*g1.z + b1.z); o1.w = f2bf((v1.w-mean)*rstd*g1.w + b1.w);
  *(ushort4*)&out[(size_t)row*512 + lane*4] = o0;
  *(ushort4*)&out[(size_t)row*512 + 256 + lane*4] = o1;
}

// ---------------------------------------------------------------- generic NT GEMM (bf16 -> f32), M=4096
// BM=64, BN=64 tiles (occupancy lever: grids 512-2048 blocks -> 2-4 blocks/CU, was 1).
// Double-buffered global_load_lds staging (32KB LDS -> 4 blocks/CU fits).
// EPI: 0 none,1 +resid,4 bf16 out,5 bias+resid,6 bias+resid -> outf2(d_out)+outb(bf16),
//      8 outf -= |scal|*v, 9 ffn fused (Wr|Wi|Wg), 10 attn fused (Wp|Wv),
//     11 pi-permuted f32 store (reservoir u), 12 sheaf1: v+bias-shift_idx(x4b) -> T[r*2048+gc]
template<int EPI>
__global__ __launch_bounds__(256,4) void gemm_nt(
  const u16* __restrict__ A, const u16* __restrict__ Bw, int K, int ldc,
  float* __restrict__ outf, u16* __restrict__ outb,
  const float* __restrict__ bias, const float* __restrict__ resid,
  const float* __restrict__ aux, float* __restrict__ outf2,
  const float* __restrict__ scal, int shift_ad)
{
  __shared__ u16 Al[2][64*64];
  __shared__ u16 Bl[2][64*64];
  const int t = threadIdx.x;
  const int bm = blockIdx.x, bn = blockIdx.y;
  const int wid = t>>6, lane = t&63;
  const int wr = wid>>1, wc = wid&1;
  const int fr = lane&15, fq = lane>>4;
  f32x4 acc[2][2] = {};
  const int nK = K>>6;
  const u16* Ab = A + (size_t)(bm*64)*K;
  const u16* Bb = Bw + (size_t)(bn*64)*K;
  const int srow8 = t>>3;            // 0..31
  const int scol = (t&7)*8;          // u16 col
  char* AlB = (char*)Al; char* BlB = (char*)Bl;
  const int lbase = wid*1024;        // wave-uniform LDS byte base within each 4KB round
  // prologue: stage tile 0 -> buf 0
  #pragma unroll
  for(int c=0;c<2;++c)
    gl_lds16(&Ab[(size_t)(c*32+srow8)*K + scol], AlB + c*4096 + lbase);
  #pragma unroll
  for(int c=0;c<2;++c)
    gl_lds16(&Bb[(size_t)(c*32+srow8)*K + scol], BlB + c*4096 + lbase);
  asm volatile("s_waitcnt vmcnt(0)" ::: "memory");
  __builtin_amdgcn_s_barrier();
  asm volatile("" ::: "memory");
  for(int bk=0; bk<nK; ++bk){
    const int cur = bk&1, nxt = cur^1;
    if(bk+1 < nK){
      #pragma unroll
      for(int c=0;c<2;++c)
        gl_lds16(&Ab[(size_t)(c*32+srow8)*K + (bk+1)*64 + scol], AlB + nxt*8192 + c*4096 + lbase);
      #pragma unroll
      for(int c=0;c<2;++c)
        gl_lds16(&Bb[(size_t)(c*32+srow8)*K + (bk+1)*64 + scol], BlB + nxt*8192 + c*4096 + lbase);
    }
    const u16* Ac = Al[cur];
    const u16* Bc = Bl[cur];
    #pragma unroll
    for(int kk=0;kk<2;++kk){
      bf16x8 af[2], bf[2];
      #pragma unroll
      for(int m=0;m<2;++m) af[m] = *(const bf16x8*)&Ac[(wr*32+m*16+fr)*64 + kk*32 + fq*8];
      #pragma unroll
      for(int n=0;n<2;++n) bf[n] = *(const bf16x8*)&Bc[(wc*32+n*16+fr)*64 + kk*32 + fq*8];
      #pragma unroll
      for(int m=0;m<2;++m)
        #pragma unroll
        for(int n=0;n<2;++n)
          acc[m][n] = __builtin_amdgcn_mfma_f32_16x16x32_bf16(af[m], bf[n], acc[m][n], 0,0,0);
    }
    asm volatile("s_waitcnt vmcnt(0)" ::: "memory");
    __builtin_amdgcn_s_barrier();
    asm volatile("" ::: "memory");
  }
  float alpha = 0.f;
  if(EPI==8) alpha = fabsf(scal[0]);
  #pragma unroll
  for(int m=0;m<2;++m){
    int gr0 = bm*64 + wr*32 + m*16 + fq*4;
    #pragma unroll
    for(int n=0;n<2;++n){
      int gc = bn*64 + wc*32 + n*16 + fr;
      float bv = 0.f;
      if(EPI==5||EPI==6||EPI==9||EPI==12) bv = bias[gc];
      if(EPI==10 && gc<128) bv = bias[gc];
      #pragma unroll
      for(int i=0;i<4;++i){
        int r = gr0 + i;
        float v = acc[m][n][i] + bv;
        if(EPI==1||EPI==5||EPI==6) v += resid[(size_t)r*ldc + gc];
        if(EPI==8){
          outf[(size_t)r*ldc + gc] -= alpha*v;
        } else if(EPI==9){
          if(gc<512) outf[(size_t)r*512 + gc] = v;
          else       outf2[(size_t)r*512 + gc-512] = sigm(v);
        } else if(EPI==10){
          if(gc<128) outf[(size_t)r*128 + gc] = sigm(v);
          else       outf2[(size_t)r*512 + gc-128] = v;
        } else if(EPI==11){
          int pc = (gc & ~63) | ((gc&15)<<2) | ((gc>>4)&3);
          outf[(size_t)r*512 + pc] = v;
        } else if(EPI==12){
          int idx = gc>>9;
          int ad = 3 - idx;
          int ts = r & 1023;
          float xnb = 0.f;
          if(ts >= ad) xnb = bf2f(((const u16*)aux)[(size_t)(r-ad)*512 + (gc&511)]);
          outb[(size_t)r*2048 + gc] = f2bf(v - xnb);
        } else {
          if(EPI==0||EPI==1||EPI==5) outf[(size_t)r*ldc + gc] = v;
          if(EPI==6) outf2[(size_t)r*ldc + gc] = v;
          if(EPI==4||EPI==6) outb[(size_t)r*ldc + gc] = f2bf(v);
        }
      }
    }
  }
}

// ---------------------------------------------------------------- path attention (flash style)
__global__ __launch_bounds__(128) void attn_kernel(
  const float* __restrict__ paths, const float* __restrict__ Vbuf, u16* __restrict__ ctxb)
{
  const int t = threadIdx.x;
  const int qt = blockIdx.x, bh = blockIdx.y;
  const int b = bh>>2, h = bh&3;
  const int rb = b<<10;
  const int ql = t>>2, sub = t&3;
  const int q = qt*32 + ql;
  const int wid = t>>6, lane = t&63;
  const int fr = lane&15, fq = lane>>4;
  __shared__ u16 Vl[128][72];
  __shared__ u16 Pl[32][72];
  __shared__ float pkl[64][6];
  __shared__ float scl[32];
  __shared__ float lsm[32];
  float al[5], bl[5];
  #pragma unroll
  for(int l=0;l<5;++l){
    float p = paths[(size_t)(rb+q)*128 + h*5 + l];
    al[l] = 2.f*p - 1.f; bl[l] = 1.f - p;
  }
  float m_run = -1e30f, l_run = 0.f;
  f32x4 acc[2][4] = {};
  const int nkt = (qt>>1) + 1;
  for(int kt=0; kt<nkt; ++kt){
    int k0 = kt*64;
    for(int i=t; i<320; i+=128){
      int k = i/5, l = i%5;
      pkl[k][l] = paths[(size_t)(rb+k0+k)*128 + h*5 + l];
    }
    {
      int dg = (t&31)*4, kbase = t>>5;
      #pragma unroll
      for(int i=0;i<16;++i){
        int k = kbase + i*4;
        float4 v4 = *(const float4*)&Vbuf[(size_t)(rb+k0+k)*512 + h*128 + dg];
        Vl[dg+0][k] = f2bf(v4.x); Vl[dg+1][k] = f2bf(v4.y);
        Vl[dg+2][k] = f2bf(v4.z); Vl[dg+3][k] = f2bf(v4.w);
      }
    }
    __syncthreads();
    float pj[16]; float tm = -1e30f;
    #pragma unroll
    for(int j=0;j<16;++j){
      int kidx = sub*16 + j;
      int k = k0 + kidx;
      float s;
      if(k <= q){
        float c = al[0]*pkl[kidx][0] + bl[0];
        float sa = c;
        #pragma unroll
        for(int l=1;l<5;++l){ c *= al[l]*pkl[kidx][l] + bl[l]; sa += c; }
        s = sa*0.2f;
      } else s = -1e30f;
      pj[j] = s; tm = fmaxf(tm, s);
    }
    tm = fmaxf(tm, __shfl_xor(tm,1,4));
    tm = fmaxf(tm, __shfl_xor(tm,2,4));
    float m_new = fmaxf(m_run, tm);
    float corr = __expf(m_run - m_new);
    float ls = 0.f;
    #pragma unroll
    for(int j=0;j<16;++j){
      float p = (pj[j] > -1e29f) ? __expf(pj[j]-m_new) : 0.f;
      ls += p;
      Pl[ql][sub*16+j] = f2bf(p);
    }
    l_run = l_run*corr + ls;
    m_run = m_new;
    if(sub==0) scl[ql] = corr;
    __syncthreads();
    #pragma unroll
    for(int m=0;m<2;++m){
      float c0 = scl[m*16+fq*4+0], c1 = scl[m*16+fq*4+1];
      float c2 = scl[m*16+fq*4+2], c3 = scl[m*16+fq*4+3];
      #pragma unroll
      for(int n=0;n<4;++n){ acc[m][n][0]*=c0; acc[m][n][1]*=c1; acc[m][n][2]*=c2; acc[m][n][3]*=c3; }
    }
    #pragma unroll
    for(int kk=0;kk<2;++kk){
      bf16x8 af[2], bf[4];
      #pragma unroll
      for(int m=0;m<2;++m) af[m] = *(const bf16x8*)&Pl[m*16+fr][kk*32+fq*8];
      #pragma unroll
      for(int n=0;n<4;++n) bf[n] = *(const bf16x8*)&Vl[wid*64+n*16+fr][kk*32+fq*8];
      #pragma unroll
      for(int m=0;m<2;++m)
        #pragma unroll
        for(int n=0;n<4;++n)
          acc[m][n] = __builtin_amdgcn_mfma_f32_16x16x32_bf16(af[m], bf[n], acc[m][n], 0,0,0);
    }
    __syncthreads();
  }
  {
    float lt = l_run + __shfl_xor(l_run,1,4);
    lt += __shfl_xor(lt,2,4);
    if(sub==0) lsm[ql] = lt;
  }
  __syncthreads();
  #pragma unroll
  for(int m=0;m<2;++m){
    float inv[4];
    #pragma unroll
    for(int i=0;i<4;++i) inv[i] = 1.f/lsm[m*16+fq*4+i];
    #pragma unroll
    for(int n=0;n<4;++n){
      int row = rb + qt*32 + m*16 + fq*4;
      int col = h*128 + wid*64 + n*16 + fr;
      #pragma unroll
      for(int i=0;i<4;++i)
        ctxb[(size_t)(row+i)*512 + col] = f2bf(acc[m][n][i]*inv[i]);
    }
  }
}

// ---------------------------------------------------------------- power-iteration matvec
__global__ __launch_bounds__(256) void pmv(const float* __restrict__ W, const float* __restrict__ vin,
                    const float* __restrict__ ssin, float* __restrict__ vout, float* __restrict__ ssout)
{
  __shared__ float vs[512];
  int t = threadIdx.x;
  int j = blockIdx.x*16 + (t>>4), ks = t&15;
  float s = ssin[0];
  float inv = (s>0.f)? rsqrtf(s) : 1.f;
  vs[t] = vin[t]*inv; vs[t+256] = vin[t+256]*inv;
  __syncthreads();
  float p = 0.f;
  const float* wr = &W[(size_t)j*512 + ks*32];
  #pragma unroll
  for(int kk=0;kk<32;++kk) p += wr[kk]*vs[ks*32+kk];
  p += __shfl_xor(p,1,16); p += __shfl_xor(p,2,16); p += __shfl_xor(p,4,16); p += __shfl_xor(p,8,16);
  if(ks==0){ vout[j] = p; atomicAdd(ssout, p*p); }
}

// scale + i8-quantize Ws rows (per-row scale), K stored in pi-order.
__global__ __launch_bounds__(128) void scale_ws(const float* __restrict__ Wres, const float* __restrict__ ss4,
                         const float* __restrict__ logrho, signed char* __restrict__ WsQ,
                         float* __restrict__ wscale)
{
  __shared__ float wmax[2];
  int j = blockIdx.x, t = threadIdx.x;
  int fr = t&15, blk = t>>4;
  float rho_t = 1.5f * sigm(logrho[0]);
  float rho_c = sqrtf(ss4[0]);
  float sc = rho_t / fmaxf(rho_c, 1e-6f);
  float w[4];
  #pragma unroll
  for(int cg=0;cg<4;++cg) w[cg] = Wres[(size_t)j*512 + blk*64 + cg*16 + fr]*sc;
  float m = fmaxf(fmaxf(fabsf(w[0]),fabsf(w[1])), fmaxf(fabsf(w[2]),fabsf(w[3])));
  #pragma unroll
  for(int d=1; d<64; d<<=1) m = fmaxf(m, __shfl_xor(m, d));
  if((t&63)==0) wmax[t>>6] = m;
  __syncthreads();
  float rm = fmaxf(wmax[0], wmax[1]);
  float qs = (rm > 0.f) ? rm*(1.f/127.f) : 1.f;
  float inv = 1.f/qs;
  int q0 = __float2int_rn(w[0]*inv), q1 = __float2int_rn(w[1]*inv);
  int q2 = __float2int_rn(w[2]*inv), q3 = __float2int_rn(w[3]*inv);
  q0 = min(127,max(-127,q0)); q1 = min(127,max(-127,q1));
  q2 = min(127,max(-127,q2)); q3 = min(127,max(-127,q3));
  u32 pk = (u32)(q0&0xff) | ((u32)(q1&0xff)<<8) | ((u32)(q2&0xff)<<16) | ((u32)(q3&0xff)<<24);
  *(u32*)&WsQ[(size_t)j*512 + blk*64 + fr*4] = pk;
  if(t==0) wscale[j] = qs*(1.f/127.f);
}

// ---------------------------------------------------------------- reservoir scan: SINGLE workgroup
// 1024 threads = 16 waves (4 waves/SIMD), r8/r10 barrier skeleton. Each lane owns
// (batch fq, 2 pi-contiguous cols). HsB history store deferred to next iteration's top.
// Ws register/AGPR-resident i8 MFMA B-fragments (asm-pinned). 16-row zero-padded state
// tile, XOR bank-swizzle on reads, matching XOR on writes.
__global__ __launch_bounds__(1024) void scan_kernel(
  const signed char* __restrict__ WsQ, const float* __restrict__ wscale,
  const float* __restrict__ u, const float* __restrict__ leak_p,
  u16* __restrict__ HsB)
{
  const int t = threadIdx.x;
  const int w = t>>6, lane = t&63, fr = lane&15, fq = lane>>4;
  const float lk = sigm(leak_p[0]);
  const float omlk = 1.f - lk;
  __shared__ signed char Sl[2][16*512];        // [parity][16 rows][512] i8; rows !=4b stay 0
  for(int i=t; i<4096; i+=1024) ((u32*)Sl)[i] = 0u;
  // lane owns batch fq, pi-positions pc = w*32 + fr*2 + {0,1}
  const int pbase = w*32 + fr*2;
  float mysc[2];
  i32x4 bw[2][8];
  #pragma unroll
  for(int cg=0; cg<2; ++cg){
    int pc = pbase + cg;
    int oc = (pc & ~63) | ((pc&3)<<4) | ((pc>>2)&15);   // inverse-pi: orig col
    mysc[cg] = wscale[oc];
    #pragma unroll
    for(int ks=0; ks<8; ++ks)
      bw[cg][ks] = *(const i32x4*)&WsQ[(size_t)oc*512 + ks*64 + fq*16];
  }
  #pragma unroll
  for(int cg=0; cg<2; ++cg)
    #pragma unroll
    for(int ks=0; ks<8; ++ks)
      asm volatile("" : "+v"(bw[cg][ks]));
  float hp0 = 0.f, hp1 = 0.f;
  const float* up = u + (size_t)(fq*1024)*512 + pbase;   // pi-ordered u
  u16* hsp = HsB + (size_t)(fq*1024)*512 + pbase;        // pi-ordered Hs
  float2 uvc = *(const float2*)up;  up += 512;
  const int rdswz = ((fr&3)<<4) ^ (((fr>>2)&3)<<6);   // read-side bank swizzle for row fr
  const int woff = (4*fq)*512 + (pbase ^ (fq<<6));    // write slot (row 4fq), b16
  u32 p01v = 0u;                                      // deferred history word
  __syncthreads();
  for(int ts=0; ts<1024; ++ts){
    float2 uvn = *(const float2*)up;  up += 512;
    if(ts > 0){ *(u32*)hsp = p01v;  hsp += 512; }
    const signed char* Sb = Sl[ts&1];
    i32x4 accA[2], accB[2];
    { i32x4 z = {0,0,0,0}; accA[0]=z; accA[1]=z; accB[0]=z; accB[1]=z; }
    {
      i32x4 af[4];
      #pragma unroll
      for(int ks=0; ks<4; ++ks)
        af[ks] = *(const i32x4*)&Sb[fr*512 + ((ks*64 + fq*16) ^ rdswz)];
      #pragma unroll
      for(int ks=0; ks<4; ++ks){
        accA[0] = __builtin_amdgcn_mfma_i32_16x16x64_i8(af[ks], bw[0][ks], accA[0], 0,0,0);
        accA[1] = __builtin_amdgcn_mfma_i32_16x16x64_i8(af[ks], bw[1][ks], accA[1], 0,0,0);
      }
    }
    {
      i32x4 af[4];
      #pragma unroll
      for(int ks=0; ks<4; ++ks)
        af[ks] = *(const i32x4*)&Sb[fr*512 + (((ks+4)*64 + fq*16) ^ rdswz)];
      #pragma unroll
      for(int ks=0; ks<4; ++ks){
        accB[0] = __builtin_amdgcn_mfma_i32_16x16x64_i8(af[ks], bw[0][ks+4], accB[0], 0,0,0);
        accB[1] = __builtin_amdgcn_mfma_i32_16x16x64_i8(af[ks], bw[1][ks+4], accB[1], 0,0,0);
      }
    }
    float pre0 = (float)(accA[0][0] + accB[0][0])*mysc[0] + uvc.x;
    float pre1 = (float)(accA[1][0] + accB[1][0])*mysc[1] + uvc.y;
    float h0 = omlk*hp0 + lk*tanh_fast(pre0);
    float h1 = omlk*hp1 + lk*tanh_fast(pre1);
    hp0 = h0; hp1 = h1;
    int q0 = __float2int_rn(h0*127.f), q1 = __float2int_rn(h1*127.f);
    u16 qp = (u16)((q0&0xff) | ((q1&0xff)<<8));
    *(u16*)&Sl[(ts+1)&1][woff] = qp;
    asm volatile("v_cvt_pk_bf16_f32 %0, %1, %2" : "=v"(p01v) : "v"(h0), "v"(h1));
    uvc = uvn;
    asm volatile("s_waitcnt lgkmcnt(0)" ::: "memory");
    __builtin_amdgcn_s_barrier();
    asm volatile("" ::: "memory");
  }
  *(u32*)hsp = p01v;   // final step's history
}

// ---------------------------------------------------------------- memory attention (M=64 keys)
__global__ __launch_bounds__(256) void mem_kernel(
  const u16* __restrict__ qb, const u16* __restrict__ keysB, const u16* __restrict__ valsB,
  u16* __restrict__ ctx2b)
{
  const int t = threadIdx.x, rt = blockIdx.x;
  const int wid = t>>6, lane = t&63, fr = lane&15, fq = lane>>4;
  __shared__ float S[64][65];
  __shared__ u16 Pl[64][72];
  __shared__ u16 VT[256][72];
  {
    f32x4 accs[4] = {};
    for(int ks=0; ks<16; ++ks){
      bf16x8 bfrag = *(const bf16x8*)&keysB[(size_t)(wid*16+fr)*512 + ks*32 + fq*8];
      #pragma unroll
      for(int mt=0;mt<4;++mt){
        bf16x8 afrag = *(const bf16x8*)&qb[(size_t)(rt*64+mt*16+fr)*512 + ks*32 + fq*8];
        accs[mt] = __builtin_amdgcn_mfma_f32_16x16x32_bf16(afrag, bfrag, accs[mt], 0,0,0);
      }
    }
    #pragma unroll
    for(int mt=0;mt<4;++mt)
      #pragma unroll
      for(int i=0;i<4;++i)
        S[mt*16+fq*4+i][wid*16+fr] = accs[mt][i];
  }
  __syncthreads();
  if(t<64){
    float m = -1e30f;
    for(int j=0;j<64;++j) m = fmaxf(m, S[t][j]);
    const float scale = 0.04419417382f; // 1/sqrt(512)
    float sum = 0.f;
    for(int j=0;j<64;++j){ float p = __expf((S[t][j]-m)*scale); sum += p; S[t][j] = p; }
    float inv = 1.f/sum;
    for(int j=0;j<64;++j) Pl[t][j] = f2bf(S[t][j]*inv);
  }
  __syncthreads();
  for(int pass=0; pass<2; ++pass){
    {
      int k = t&63, cb = t>>6;
      #pragma unroll
      for(int i=0;i<8;++i){
        int d0 = (cb + i*4)*8;
        uint4 v = *(const uint4*)&valsB[(size_t)k*512 + pass*256 + d0];
        VT[d0+0][k]=(u16)(v.x); VT[d0+1][k]=(u16)(v.x>>16);
        VT[d0+2][k]=(u16)(v.y); VT[d0+3][k]=(u16)(v.y>>16);
        VT[d0+4][k]=(u16)(v.z); VT[d0+5][k]=(u16)(v.z>>16);
        VT[d0+6][k]=(u16)(v.w); VT[d0+7][k]=(u16)(v.w>>16);
      }
    }
    __syncthreads();
    f32x4 accp[4][4] = {};
    #pragma unroll
    for(int kk=0;kk<2;++kk){
      bf16x8 af[4], bf[4];
      #pragma unroll
      for(int mt=0;mt<4;++mt) af[mt] = *(const bf16x8*)&Pl[mt*16+fr][kk*32+fq*8];
      #pragma unroll
      for(int nt=0;nt<4;++nt) bf[nt] = *(const bf16x8*)&VT[wid*64+nt*16+fr][kk*32+fq*8];
      #pragma unroll
      for(int mt=0;mt<4;++mt)
        #pragma unroll
        for(int nt=0;nt<4;++nt)
          accp[mt][nt] = __builtin_amdgcn_mfma_f32_16x16x32_bf16(af[mt], bf[nt], accp[mt][nt], 0,0,0);
    }
    #pragma unroll
    for(int mt=0;mt<4;++mt)
      #pragma unroll
      for(int nt=0;nt<4;++nt){
        int row = rt*64 + mt*16 + fq*4;
        int col = pass*256 + wid*64 + nt*16 + fr;
        #pragma unroll
        for(int i=0;i<4;++i)
          ctx2b[(size_t)(row+i)*512 + col] = f2bf(accp[mt][nt][i]);
      }
    __syncthreads();
  }
}

// ---------------------------------------------------------------- ffn prod*gate -> bf16
__global__ __launch_bounds__(256) void prodgate(const float* __restrict__ ri, const float* __restrict__ g,
                         u16* __restrict__ pgb)
{
  int gi = blockIdx.x*256 + threadIdx.x;
  int row = gi>>7, c4 = (gi&127)*4;
  const float* base = ri + (size_t)row*512;
  float4 gv = *(const float4*)&g[(size_t)row*512 + c4];
  float4 o;
  if(c4 < 256){
    float4 r = *(const float4*)&base[c4];
    float4 ii = *(const float4*)&base[256+c4];
    o.x = (r.x*r.x - ii.x*ii.x)*gv.x; o.y = (r.y*r.y - ii.y*ii.y)*gv.y;
    o.z = (r.z*r.z - ii.z*ii.z)*gv.z; o.w = (r.w*r.w - ii.w*ii.w)*gv.w;
  } else {
    float4 r = *(const float4*)&base[c4-256];
    float4 ii = *(const float4*)&base[c4];
    o.x = 2.f*r.x*ii.x*gv.x; o.y = 2.f*r.y*ii.y*gv.y;
    o.z = 2.f*r.z*ii.z*gv.z; o.w = 2.f*r.w*ii.w*gv.w;
  }
  ushort4 us; us.x=f2bf(o.x); us.y=f2bf(o.y); us.z=f2bf(o.z); us.w=f2bf(o.w);
  *(ushort4*)&pgb[(size_t)row*512 + c4] = us;
}

// ================================================================ host
static void launch_gemm(int epi, dim3 grid, const u16* A, const u16* B, int K, int ldc,
  float* outf, u16* outb, const float* bias, const float* resid, const float* aux,
  float* outf2, const float* scal, int ad, hipStream_t s)
{
  switch(epi){
    case 0: gemm_nt<0><<<grid,256,0,s>>>(A,B,K,ldc,outf,outb,bias,resid,aux,outf2,scal,ad); break;
    case 1: gemm_nt<1><<<grid,256,0,s>>>(A,B,K,ldc,outf,outb,bias,resid,aux,outf2,scal,ad); break;
    case 4: gemm_nt<4><<<grid,256,0,s>>>(A,B,K,ldc,outf,outb,bias,resid,aux,outf2,scal,ad); break;
    case 5: gemm_nt<5><<<grid,256,0,s>>>(A,B,K,ldc,outf,outb,bias,resid,aux,outf2,scal,ad); break;
    case 6: gemm_nt<6><<<grid,256,0,s>>>(A,B,K,ldc,outf,outb,bias,resid,aux,outf2,scal,ad); break;
    case 8: gemm_nt<8><<<grid,256,0,s>>>(A,B,K,ldc,outf,outb,bias,resid,aux,outf2,scal,ad); break;
    case 9: gemm_nt<9><<<grid,256,0,s>>>(A,B,K,ldc,outf,outb,bias,resid,aux,outf2,scal,ad); break;
    case 10: gemm_nt<10><<<grid,256,0,s>>>(A,B,K,ldc,outf,outb,bias,resid,aux,outf2,scal,ad); break;
    case 11: gemm_nt<11><<<grid,256,0,s>>>(A,B,K,ldc,outf,outb,bias,resid,aux,outf2,scal,ad); break;
    case 12: gemm_nt<12><<<grid,256,0,s>>>(A,B,K,ldc,outf,outb,bias,resid,aux,outf2,scal,ad); break;
  }
}

extern "C" void kernel_launch(void* const* d_in, const int* in_sizes, int n_in,
                              void* d_out, int out_size, void* d_ws, size_t ws_size,
                              hipStream_t stream)
{
  const float* x      = (const float*)d_in[0];
  const float* ln1g   = (const float*)d_in[1];  const float* ln1b = (const float*)d_in[2];
  const float* ln2g   = (const float*)d_in[3];  const float* ln2b = (const float*)d_in[4];
  const float* ln3g   = (const float*)d_in[5];  const float* ln3b = (const float*)d_in[6];
  const float* ln4g   = (const float*)d_in[7];  const float* ln4b = (const float*)d_in[8];
  const float* aWp    = (const float*)d_in[9];  const float* abp  = (const float*)d_in[10];
  const float* aWv    = (const float*)d_in[11]; const float* aWo  = (const float*)d_in[12];
  const float* fWr    = (const float*)d_in[13]; const float* fbr  = (const float*)d_in[14];
  const float* fWi    = (const float*)d_in[15]; const float* fbi  = (const float*)d_in[16];
  const float* fWg    = (const float*)d_in[17]; const float* fbg  = (const float*)d_in[18];
  const float* fWo    = (const float*)d_in[19]; const float* fbo  = (const float*)d_in[20];
  const float* rWin   = (const float*)d_in[21]; const float* rWres= (const float*)d_in[22];
  const float* rlogr  = (const float*)d_in[23]; const float* rleak= (const float*)d_in[24];
  const float* rread  = (const float*)d_in[25]; const float* rv0  = (const float*)d_in[26];
  const float* mkeys  = (const float*)d_in[27]; const float* mvals= (const float*)d_in[28];
  const float* mWq    = (const float*)d_in[29]; const float* mWo  = (const float*)d_in[30];
  const float* mbo    = (const float*)d_in[31];
  const float* sRw    = (const float*)d_in[32]; const float* sRb  = (const float*)d_in[33];
  const float* salpha = (const float*)d_in[34];
  (void)in_sizes; (void)n_in; (void)out_size;

  char* ws = (char*)d_ws;
  float* XCUR  = (float*)(ws + 0);               // x1..x3 running residual
  u16*   X4B   = (u16*)  (ws + 8388608);         // bf16 x4 (HB region; HB dead by then)
  u16*   HB    = (u16*)  (ws + 8388608);         // ln outputs
  float* VU    = (float*)(ws + 12582912);        // V / u(pi) / ri
  u16*   TBUF  = (u16*)  (ws + 12582912);        // sheaf T [4096][2048] bf16 = 16MB
                                                 //   (VU/PATHS/CTXB/HSB all dead at sheaf)
  float* PATHS = (float*)(ws + 20971520);
  u16*   CTXB  = (u16*)  (ws + 23068672);        // ctx / qb / pgb
  u16*   HSB   = (u16*)  (ws + 27262976);        // Hs(pi cols) / ctx2b
  char* WB = ws + 31457280;
  u16* WpB   = (u16*)(WB + 0);                   // 128 rows } contiguous 640-row block
  u16* WvB   = (u16*)(WB + 131072);              // 512 rows }
  u16* WoB   = (u16*)(WB + 655360);
  u16* WinB  = (u16*)(WB + 1179648);
  u16* rdB   = (u16*)(WB + 1703936);             // K in pi-order
  u16* WqB   = (u16*)(WB + 2228224);
  u16* keysB = (u16*)(WB + 2752512);
  u16* valsB = (u16*)(WB + 2818048);
  u16* mWoB  = (u16*)(WB + 2883584);
  u16* WrB   = (u16*)(WB + 3407872);             // 256 rows } contiguous 1024-row block
  u16* WiB   = (u16*)(WB + 3670016);             // 256 rows }
  u16* WgB   = (u16*)(WB + 3932160);             // 512 rows }
  u16* fWoB  = (u16*)(WB + 4456448);
  u16* RwB   = (u16*)(WB + 4980736);             // 2048 rows contiguous (sheaf-1 fused B)
  u16* RwTB  = (u16*)(WB + 7077888);             // RwT' [512][2048] (sheaf-2 fused B)
  signed char* WsQ = (signed char*)(WB + 9175040); // 512x512 i8, K pi-order
  float* wscale = (float*)(WB + 9437184);
  float* bpp = (float*)(WB + 9699328);             // 128 f32 (padded attn path bias)
  float* bpc = (float*)(WB + 9699840);             // 1024 f32 (ffn concat bias)
  float* ssv = (float*)(WB + 9733632);
  float* vr  = (float*)(WB + 9733696);             // 4 x 512 f32
  float* GATE = (float*)d_out;                     // gate scratch, overwritten by x4 later

  if(ws_size < (size_t)41200000) return;

  prep_weights<<<6915,128,0,stream>>>(aWp,aWv,aWo,rWin,rread,mWq,mkeys,mvals,mWo,fWr,fWi,fWg,fWo,sRw,
      abp, fbr, fbi, fbg,
      WpB,WvB,WoB,WinB,rdB,WqB,keysB,valsB,mWoB,WrB,WiB,WgB,fWoB,RwB,bpp,bpc,ssv);
  transpose_rw<<<dim3(16,16,4),256,0,stream>>>(sRw, RwTB);

  dim3 g512(64,8), g640(64,10), g1024(64,16), g2048(64,32);

  // ---- attention (Wp+Wv fused)
  ln_kernel<<<4096,64,0,stream>>>(x, ln1g, ln1b, HB);
  launch_gemm(10, g640, HB, WpB, 512, 0, PATHS, nullptr, bpp, nullptr, nullptr, VU, nullptr, 0, stream);
  attn_kernel<<<dim3(32,16),128,0,stream>>>(PATHS, VU, CTXB);
  launch_gemm(1, g512, CTXB, WoB, 512, 512, XCUR, nullptr, nullptr, x, nullptr, nullptr, nullptr, 0, stream);

  // ---- reservoir (u written in pi-order via EPI11)
  ln_kernel<<<4096,64,0,stream>>>(XCUR, ln2g, ln2b, HB);
  launch_gemm(11, g512, HB, WinB, 512, 512, VU, nullptr, nullptr, nullptr, nullptr, nullptr, nullptr, 0, stream);
  pmv<<<32,256,0,stream>>>(rWres, rv0,   &ssv[0], &vr[0],    &ssv[1]);
  pmv<<<32,256,0,stream>>>(rWres, &vr[0],   &ssv[1], &vr[512],  &ssv[2]);
  pmv<<<32,256,0,stream>>>(rWres, &vr[512], &ssv[2], &vr[1024], &ssv[3]);
  pmv<<<32,256,0,stream>>>(rWres, &vr[1024],&ssv[3], &vr[1536], &ssv[4]);
  scale_ws<<<512,128,0,stream>>>(rWres, &ssv[4], rlogr, WsQ, wscale);
  scan_kernel<<<1,1024,0,stream>>>(WsQ, wscale, VU, rleak, HSB);
  launch_gemm(1, g512, HSB, rdB, 512, 512, XCUR, nullptr, nullptr, XCUR, nullptr, nullptr, nullptr, 0, stream);

  // ---- memory
  ln_kernel<<<4096,64,0,stream>>>(XCUR, ln3g, ln3b, HB);
  launch_gemm(4, g512, HB, WqB, 512, 512, nullptr, CTXB, nullptr, nullptr, nullptr, nullptr, nullptr, 0, stream);
  mem_kernel<<<64,256,0,stream>>>(CTXB, keysB, valsB, HSB);
  launch_gemm(5, g512, HSB, mWoB, 512, 512, XCUR, nullptr, mbo, XCUR, nullptr, nullptr, nullptr, 0, stream);

  // ---- ffn (Wr+Wi+Wg fused)
  ln_kernel<<<4096,64,0,stream>>>(XCUR, ln4g, ln4b, HB);
  launch_gemm(9, g1024, HB, WrB, 512, 0, VU, nullptr, bpc, nullptr, nullptr, GATE, nullptr, 0, stream);
  prodgate<<<2048,256,0,stream>>>(VU, GATE, CTXB);
  // x4 = x3 + ffn_out -> d_out (f32) + X4B (bf16, in dead HB region)
  launch_gemm(6, g512, CTXB, fWoB, 512, 512, nullptr, X4B, fbo, XCUR, nullptr, (float*)d_out, nullptr, 0, stream);

  // ---- sheaf, 2 fused GEMMs:
  // T[r][idx*512+c] = (x4@Rw_idx^T)[r][c] + Rb[idx][c] - shift_idx(x4)[r][c]   (EPI12, bf16)
  launch_gemm(12, g2048, X4B, RwB, 512, 0, nullptr, TBUF, sRb, nullptr, (const float*)X4B, nullptr, nullptr, 0, stream);
  // d_out -= |alpha| * T @ RwT'   (K=2048 contraction == sum over idx of T_idx@Rw_idx)
  launch_gemm(8, g512, TBUF, RwTB, 2048, 512, (float*)d_out, nullptr, nullptr, nullptr, nullptr, nullptr, salpha, 0, stream);
}

// Round 13
// 1121.909 us; speedup vs baseline: 1.0424x; 1.0174x over previous
//
#include <hip/hip_runtime.h>
#include <hip/hip_bf16.h>
#include <stdint.h>

typedef unsigned short u16;
typedef unsigned int u32;
typedef unsigned long long u64;
typedef __bf16 bf16x8 __attribute__((ext_vector_type(8)));
typedef float f32x4 __attribute__((ext_vector_type(4)));
typedef int i32x4 __attribute__((ext_vector_type(4)));

__device__ __forceinline__ u16 f2bf(float f){
  unsigned u = __float_as_uint(f);
  u += 0x7fffu + ((u>>16)&1u);
  return (u16)(u>>16);
}
__device__ __forceinline__ float bf2f(u16 h){ return __uint_as_float((u32)h<<16); }
__device__ __forceinline__ float sigm(float x){ return 1.f/(1.f+__expf(-x)); }
__device__ __forceinline__ float tanh_fast(float x){ float e = __expf(2.f*x); return 1.f - 2.f/(e+1.f); }

// async global->LDS, 16B per lane; LDS dest = wave-uniform base + lane*16
__device__ __forceinline__ void gl_lds16(const void* g, void* l){
  __builtin_amdgcn_global_load_lds((const __attribute__((address_space(1))) void*)g,
                                   (__attribute__((address_space(3))) void*)l, 16, 0, 0);
}

// Global K-permutation pi used by the reservoir path (makes each scan lane's values
// contiguous): within each 64-block, c = cg*16+fr  ->  fr*4+cg.
// Applied consistently to: WsQ K-dim, scan LDS state, u columns (EPI11), HsB columns,
// rdB K-dim. All consumers contract over this axis -> identity transformation.

// ---------------------------------------------------------------- prep weights
__global__ __launch_bounds__(128) void prep_weights(
  const float* Wp, const float* Wv, const float* Wo, const float* Win, const float* rd,
  const float* Wq, const float* keys, const float* vals, const float* mWo,
  const float* Wr, const float* Wi, const float* Wg, const float* fWo, const float* Rw,
  const float* bp, const float* fbr, const float* fbi, const float* fbg,
  u16* WpB, u16* WvB, u16* WoB, u16* WinB, u16* rdB,
  u16* WqB, u16* keysB, u16* valsB, u16* mWoB,
  u16* WrB, u16* WiB, u16* WgB, u16* fWoB, u16* RwB,
  float* bpp, float* bpc, float* ss)
{
  int blk = blockIdx.x, t = threadIdx.x;
  if(blk==6912){ if(t<128) bpp[t] = (t<20)? bp[t] : 0.f; return; }
  if(blk==6913){
    for(int j=t; j<1024; j+=128)
      bpc[j] = (j<256)? fbr[j] : (j<512)? fbi[j-256] : fbg[j-512];
    return;
  }
  if(blk==6914){ if(t==0) ss[0]=1.f; else if(t<5) ss[t]=0.f; return; }
  const float* src = nullptr; u16* dst = nullptr; int r;
  bool perm = false;
  if(blk<128){ r=blk; dst=WpB+(size_t)r*512; if(r<20) src=Wp+(size_t)r*512; }
  else if(blk<640){ r=blk-128; dst=WvB+(size_t)r*512; src=Wv+(size_t)r*512; }
  else if(blk<1152){ r=blk-640; dst=WoB+(size_t)r*512; src=Wo+(size_t)r*512; }
  else if(blk<1664){ r=blk-1152; dst=WinB+(size_t)r*512; src=Win+(size_t)r*512; }
  else if(blk<2176){ r=blk-1664; dst=rdB+(size_t)r*512; src=rd+(size_t)r*512; perm=true; }
  else if(blk<2688){ r=blk-2176; dst=WqB+(size_t)r*512; src=Wq+(size_t)r*512; }
  else if(blk<2752){ r=blk-2688; dst=keysB+(size_t)r*512; src=keys+(size_t)r*512; }
  else if(blk<2816){ r=blk-2752; dst=valsB+(size_t)r*512; src=vals+(size_t)r*512; }
  else if(blk<3328){ r=blk-2816; dst=mWoB+(size_t)r*512; src=mWo+(size_t)r*512; }
  else if(blk<3584){ r=blk-3328; dst=WrB+(size_t)r*512; src=Wr+(size_t)r*512; }
  else if(blk<3840){ r=blk-3584; dst=WiB+(size_t)r*512; src=Wi+(size_t)r*512; }
  else if(blk<4352){ r=blk-3840; dst=WgB+(size_t)r*512; src=Wg+(size_t)r*512; }
  else if(blk<4864){ r=blk-4352; dst=fWoB+(size_t)r*512; src=fWo+(size_t)r*512; }
  else { r=blk-4864; dst=RwB+(size_t)r*512; src=Rw+(size_t)r*512; }
  if(src){
    float4 a = *(const float4*)&src[t*4];
    ushort4 o; o.x=f2bf(a.x); o.y=f2bf(a.y); o.z=f2bf(a.z); o.w=f2bf(a.w);
    if(perm){
      // pi-scatter: k=t*4+e -> (k&~63) | ((k&15)<<2) | ((k>>4)&3); stride 4 per e
      int k0 = t*4;
      int base = (k0 & ~63) | ((k0&15)<<2) | ((k0>>4)&3);
      dst[base] = o.x; dst[base+4] = o.y; dst[base+8] = o.z; dst[base+12] = o.w;
    } else {
      *(ushort4*)&dst[t*4] = o;
    }
  } else {
    ushort4 z; z.x=0; z.y=0; z.z=0; z.w=0;
    *(ushort4*)&dst[t*4] = z;
  }
}

// transpose sheaf_Rw -> RwT' [512 out-cols][2048 K] with K = z*512 + k  (K-concat layout
// for the single fused sheaf-2 GEMM)
__global__ __launch_bounds__(256) void transpose_rw(const float* __restrict__ Rw, u16* __restrict__ RwT){
  __shared__ float tl[32][33];
  int z = blockIdx.z, it = blockIdx.x, jt = blockIdx.y;
  const float* src = Rw + (size_t)z*262144;
  int r = threadIdx.x>>3, c4 = (threadIdx.x&7)*4;
  float4 v = *(const float4*)&src[(size_t)(jt*32+r)*512 + it*32 + c4];
  tl[r][c4+0]=v.x; tl[r][c4+1]=v.y; tl[r][c4+2]=v.z; tl[r][c4+3]=v.w;
  __syncthreads();
  ushort4 o;
  o.x = f2bf(tl[c4+0][r]); o.y = f2bf(tl[c4+1][r]);
  o.z = f2bf(tl[c4+2][r]); o.w = f2bf(tl[c4+3][r]);
  *(ushort4*)&RwT[(size_t)(it*32+r)*2048 + z*512 + jt*32 + c4] = o;
}

// ---------------------------------------------------------------- layernorm -> bf16
// 256 threads = 4 waves, one row per wave (identical per-wave math as the 64-thread
// version -> bit-identical output), grid 1024.
__global__ __launch_bounds__(256) void ln_kernel(const float* __restrict__ x, const float* __restrict__ g,
      const float* __restrict__ b, u16* __restrict__ out)
{
  int row = blockIdx.x*4 + (threadIdx.x>>6), lane = threadIdx.x&63;
  const float* xr = x + (size_t)row*512;
  float4 v0 = *(const float4*)&xr[lane*4];
  float4 v1 = *(const float4*)&xr[256+lane*4];
  float s = v0.x+v0.y+v0.z+v0.w + v1.x+v1.y+v1.z+v1.w;
  float q = v0.x*v0.x+v0.y*v0.y+v0.z*v0.z+v0.w*v0.w + v1.x*v1.x+v1.y*v1.y+v1.z*v1.z+v1.w*v1.w;
  #pragma unroll
  for(int m=1;m<64;m<<=1){ s += __shfl_xor(s,m); q += __shfl_xor(q,m); }
  float mean = s*(1.f/512.f);
  float var  = q*(1.f/512.f) - mean*mean;
  float rstd = rsqrtf(var + 1e-5f);
  float4 g0 = *(const float4*)&g[lane*4], g1 = *(const float4*)&g[256+lane*4];
  float4 b0 = *(const float4*)&b[lane*4], b1 = *(const float4*)&b[256+lane*4];
  ushort4 o0, o1;
  o0.x = f2bf((v0.x-mean)*rstd*g0.x + b0.x); o0.y = f2bf((v0.y-mean)*rstd*g0.y + b0.y);
  o0.z = f2bf((v0.z-mean)*rstd*g0.z + b0.z); o0.w = f2bf((v0.w-mean)*rstd*g0.w + b0.w);
  o1.x = f2bf((v1.x-mean)*rstd*g1.x + b1.x); o1.y = f2bf((v1.y-mean)*rstd*g1.y + b1.y);
  o1.z = f2bf((v1.z-mean)*rstd*g1.z + b1.z); o1.w = f2bf((v1.w-mean)*rstd*g1.w + b1.w);
  *(ushort4*)&out[(size_t)row*512 + lane*4] = o0;
  *(ushort4*)&out[(size_t)row*512 + 256 + lane*4] = o1;
}

// ---------------------------------------------------------------- generic NT GEMM (bf16 -> f32), M=4096
// BM=64, BN=64 tiles (grids 512-2048 blocks -> 2-4 blocks/CU).
// Double-buffered global_load_lds staging (32KB LDS).
// EPI: 0 none,1 +resid,4 bf16 out,5 bias+resid,6 bias+resid -> outf2(d_out)+outb(bf16),
//      8 outf -= |scal|*v, 9 ffn fused (Wr|Wi|Wg), 10 attn fused (Wp|Wv),
//     11 pi-permuted f32 store (reservoir u), 12 sheaf1: v+bias-shift_idx(x4b) -> T[r*2048+gc]
template<int EPI>
__global__ __launch_bounds__(256,4) void gemm_nt(
  const u16* __restrict__ A, const u16* __restrict__ Bw, int K, int ldc,
  float* __restrict__ outf, u16* __restrict__ outb,
  const float* __restrict__ bias, const float* __restrict__ resid,
  const float* __restrict__ aux, float* __restrict__ outf2,
  const float* __restrict__ scal, int shift_ad)
{
  __shared__ u16 Al[2][64*64];
  __shared__ u16 Bl[2][64*64];
  const int t = threadIdx.x;
  const int bm = blockIdx.x, bn = blockIdx.y;
  const int wid = t>>6, lane = t&63;
  const int wr = wid>>1, wc = wid&1;
  const int fr = lane&15, fq = lane>>4;
  f32x4 acc[2][2] = {};
  const int nK = K>>6;
  const u16* Ab = A + (size_t)(bm*64)*K;
  const u16* Bb = Bw + (size_t)(bn*64)*K;
  const int srow8 = t>>3;            // 0..31
  const int scol = (t&7)*8;          // u16 col
  char* AlB = (char*)Al; char* BlB = (char*)Bl;
  const int lbase = wid*1024;        // wave-uniform LDS byte base within each 4KB round
  // prologue: stage tile 0 -> buf 0
  #pragma unroll
  for(int c=0;c<2;++c)
    gl_lds16(&Ab[(size_t)(c*32+srow8)*K + scol], AlB + c*4096 + lbase);
  #pragma unroll
  for(int c=0;c<2;++c)
    gl_lds16(&Bb[(size_t)(c*32+srow8)*K + scol], BlB + c*4096 + lbase);
  asm volatile("s_waitcnt vmcnt(0)" ::: "memory");
  __builtin_amdgcn_s_barrier();
  asm volatile("" ::: "memory");
  for(int bk=0; bk<nK; ++bk){
    const int cur = bk&1, nxt = cur^1;
    if(bk+1 < nK){
      #pragma unroll
      for(int c=0;c<2;++c)
        gl_lds16(&Ab[(size_t)(c*32+srow8)*K + (bk+1)*64 + scol], AlB + nxt*8192 + c*4096 + lbase);
      #pragma unroll
      for(int c=0;c<2;++c)
        gl_lds16(&Bb[(size_t)(c*32+srow8)*K + (bk+1)*64 + scol], BlB + nxt*8192 + c*4096 + lbase);
    }
    const u16* Ac = Al[cur];
    const u16* Bc = Bl[cur];
    #pragma unroll
    for(int kk=0;kk<2;++kk){
      bf16x8 af[2], bf[2];
      #pragma unroll
      for(int m=0;m<2;++m) af[m] = *(const bf16x8*)&Ac[(wr*32+m*16+fr)*64 + kk*32 + fq*8];
      #pragma unroll
      for(int n=0;n<2;++n) bf[n] = *(const bf16x8*)&Bc[(wc*32+n*16+fr)*64 + kk*32 + fq*8];
      #pragma unroll
      for(int m=0;m<2;++m)
        #pragma unroll
        for(int n=0;n<2;++n)
          acc[m][n] = __builtin_amdgcn_mfma_f32_16x16x32_bf16(af[m], bf[n], acc[m][n], 0,0,0);
    }
    asm volatile("s_waitcnt vmcnt(0)" ::: "memory");
    __builtin_amdgcn_s_barrier();
    asm volatile("" ::: "memory");
  }
  float alpha = 0.f;
  if(EPI==8) alpha = fabsf(scal[0]);
  #pragma unroll
  for(int m=0;m<2;++m){
    int gr0 = bm*64 + wr*32 + m*16 + fq*4;
    #pragma unroll
    for(int n=0;n<2;++n){
      int gc = bn*64 + wc*32 + n*16 + fr;
      float bv = 0.f;
      if(EPI==5||EPI==6||EPI==9||EPI==12) bv = bias[gc];
      if(EPI==10 && gc<128) bv = bias[gc];
      #pragma unroll
      for(int i=0;i<4;++i){
        int r = gr0 + i;
        float v = acc[m][n][i] + bv;
        if(EPI==1||EPI==5||EPI==6) v += resid[(size_t)r*ldc + gc];
        if(EPI==8){
          outf[(size_t)r*ldc + gc] -= alpha*v;
        } else if(EPI==9){
          if(gc<512) outf[(size_t)r*512 + gc] = v;
          else       outf2[(size_t)r*512 + gc-512] = sigm(v);
        } else if(EPI==10){
          if(gc<128) outf[(size_t)r*128 + gc] = sigm(v);
          else       outf2[(size_t)r*512 + gc-128] = v;
        } else if(EPI==11){
          int pc = (gc & ~63) | ((gc&15)<<2) | ((gc>>4)&3);
          outf[(size_t)r*512 + pc] = v;
        } else if(EPI==12){
          int idx = gc>>9;
          int ad = 3 - idx;
          int ts = r & 1023;
          float xnb = 0.f;
          if(ts >= ad) xnb = bf2f(((const u16*)aux)[(size_t)(r-ad)*512 + (gc&511)]);
          outb[(size_t)r*2048 + gc] = f2bf(v - xnb);
        } else {
          if(EPI==0||EPI==1||EPI==5) outf[(size_t)r*ldc + gc] = v;
          if(EPI==6) outf2[(size_t)r*ldc + gc] = v;
          if(EPI==4||EPI==6) outb[(size_t)r*ldc + gc] = f2bf(v);
        }
      }
    }
  }
}

// ---------------------------------------------------------------- path attention (flash style)
// grid (bh=16, qt=32): with 512 blocks on 256 CUs, co-resident pairs are (qt, qt+16)
// instead of (qt, qt) -> per-CU work totals 10..17.5 tile-units instead of 2..32
// (work ~ qt/2+1). Pure load-balance change; math identical.
__global__ __launch_bounds__(128) void attn_kernel(
  const float* __restrict__ paths, const float* __restrict__ Vbuf, u16* __restrict__ ctxb)
{
  const int t = threadIdx.x;
  const int qt = blockIdx.y, bh = blockIdx.x;
  const int b = bh>>2, h = bh&3;
  const int rb = b<<10;
  const int ql = t>>2, sub = t&3;
  const int q = qt*32 + ql;
  const int wid = t>>6, lane = t&63;
  const int fr = lane&15, fq = lane>>4;
  __shared__ u16 Vl[128][72];
  __shared__ u16 Pl[32][72];
  __shared__ float pkl[64][6];
  __shared__ float scl[32];
  __shared__ float lsm[32];
  float al[5], bl[5];
  #pragma unroll
  for(int l=0;l<5;++l){
    float p = paths[(size_t)(rb+q)*128 + h*5 + l];
    al[l] = 2.f*p - 1.f; bl[l] = 1.f - p;
  }
  float m_run = -1e30f, l_run = 0.f;
  f32x4 acc[2][4] = {};
  const int nkt = (qt>>1) + 1;
  for(int kt=0; kt<nkt; ++kt){
    int k0 = kt*64;
    for(int i=t; i<320; i+=128){
      int k = i/5, l = i%5;
      pkl[k][l] = paths[(size_t)(rb+k0+k)*128 + h*5 + l];
    }
    {
      int dg = (t&31)*4, kbase = t>>5;
      #pragma unroll
      for(int i=0;i<16;++i){
        int k = kbase + i*4;
        float4 v4 = *(const float4*)&Vbuf[(size_t)(rb+k0+k)*512 + h*128 + dg];
        Vl[dg+0][k] = f2bf(v4.x); Vl[dg+1][k] = f2bf(v4.y);
        Vl[dg+2][k] = f2bf(v4.z); Vl[dg+3][k] = f2bf(v4.w);
      }
    }
    __syncthreads();
    float pj[16]; float tm = -1e30f;
    #pragma unroll
    for(int j=0;j<16;++j){
      int kidx = sub*16 + j;
      int k = k0 + kidx;
      float s;
      if(k <= q){
        float c = al[0]*pkl[kidx][0] + bl[0];
        float sa = c;
        #pragma unroll
        for(int l=1;l<5;++l){ c *= al[l]*pkl[kidx][l] + bl[l]; sa += c; }
        s = sa*0.2f;
      } else s = -1e30f;
      pj[j] = s; tm = fmaxf(tm, s);
    }
    tm = fmaxf(tm, __shfl_xor(tm,1,4));
    tm = fmaxf(tm, __shfl_xor(tm,2,4));
    float m_new = fmaxf(m_run, tm);
    float corr = __expf(m_run - m_new);
    float ls = 0.f;
    #pragma unroll
    for(int j=0;j<16;++j){
      float p = (pj[j] > -1e29f) ? __expf(pj[j]-m_new) : 0.f;
      ls += p;
      Pl[ql][sub*16+j] = f2bf(p);
    }
    l_run = l_run*corr + ls;
    m_run = m_new;
    if(sub==0) scl[ql] = corr;
    __syncthreads();
    #pragma unroll
    for(int m=0;m<2;++m){
      float c0 = scl[m*16+fq*4+0], c1 = scl[m*16+fq*4+1];
      float c2 = scl[m*16+fq*4+2], c3 = scl[m*16+fq*4+3];
      #pragma unroll
      for(int n=0;n<4;++n){ acc[m][n][0]*=c0; acc[m][n][1]*=c1; acc[m][n][2]*=c2; acc[m][n][3]*=c3; }
    }
    #pragma unroll
    for(int kk=0;kk<2;++kk){
      bf16x8 af[2], bf[4];
      #pragma unroll
      for(int m=0;m<2;++m) af[m] = *(const bf16x8*)&Pl[m*16+fr][kk*32+fq*8];
      #pragma unroll
      for(int n=0;n<4;++n) bf[n] = *(const bf16x8*)&Vl[wid*64+n*16+fr][kk*32+fq*8];
      #pragma unroll
      for(int m=0;m<2;++m)
        #pragma unroll
        for(int n=0;n<4;++n)
          acc[m][n] = __builtin_amdgcn_mfma_f32_16x16x32_bf16(af[m], bf[n], acc[m][n], 0,0,0);
    }
    __syncthreads();
  }
  {
    float lt = l_run + __shfl_xor(l_run,1,4);
    lt += __shfl_xor(lt,2,4);
    if(sub==0) lsm[ql] = lt;
  }
  __syncthreads();
  #pragma unroll
  for(int m=0;m<2;++m){
    float inv[4];
    #pragma unroll
    for(int i=0;i<4;++i) inv[i] = 1.f/lsm[m*16+fq*4+i];
    #pragma unroll
    for(int n=0;n<4;++n){
      int row = rb + qt*32 + m*16 + fq*4;
      int col = h*128 + wid*64 + n*16 + fr;
      #pragma unroll
      for(int i=0;i<4;++i)
        ctxb[(size_t)(row+i)*512 + col] = f2bf(acc[m][n][i]*inv[i]);
    }
  }
}

// ---------------------------------------------------------------- power-iteration matvec
__global__ __launch_bounds__(256) void pmv(const float* __restrict__ W, const float* __restrict__ vin,
                    const float* __restrict__ ssin, float* __restrict__ vout, float* __restrict__ ssout)
{
  __shared__ float vs[512];
  int t = threadIdx.x;
  int j = blockIdx.x*16 + (t>>4), ks = t&15;
  float s = ssin[0];
  float inv = (s>0.f)? rsqrtf(s) : 1.f;
  vs[t] = vin[t]*inv; vs[t+256] = vin[t+256]*inv;
  __syncthreads();
  float p = 0.f;
  const float* wr = &W[(size_t)j*512 + ks*32];
  #pragma unroll
  for(int kk=0;kk<32;++kk) p += wr[kk]*vs[ks*32+kk];
  p += __shfl_xor(p,1,16); p += __shfl_xor(p,2,16); p += __shfl_xor(p,4,16); p += __shfl_xor(p,8,16);
  if(ks==0){ vout[j] = p; atomicAdd(ssout, p*p); }
}

// scale + i8-quantize Ws rows (per-row scale), K stored in pi-order.
__global__ __launch_bounds__(128) void scale_ws(const float* __restrict__ Wres, const float* __restrict__ ss4,
                         const float* __restrict__ logrho, signed char* __restrict__ WsQ,
                         float* __restrict__ wscale)
{
  __shared__ float wmax[2];
  int j = blockIdx.x, t = threadIdx.x;
  int fr = t&15, blk = t>>4;
  float rho_t = 1.5f * sigm(logrho[0]);
  float rho_c = sqrtf(ss4[0]);
  float sc = rho_t / fmaxf(rho_c, 1e-6f);
  float w[4];
  #pragma unroll
  for(int cg=0;cg<4;++cg) w[cg] = Wres[(size_t)j*512 + blk*64 + cg*16 + fr]*sc;
  float m = fmaxf(fmaxf(fabsf(w[0]),fabsf(w[1])), fmaxf(fabsf(w[2]),fabsf(w[3])));
  #pragma unroll
  for(int d=1; d<64; d<<=1) m = fmaxf(m, __shfl_xor(m, d));
  if((t&63)==0) wmax[t>>6] = m;
  __syncthreads();
  float rm = fmaxf(wmax[0], wmax[1]);
  float qs = (rm > 0.f) ? rm*(1.f/127.f) : 1.f;
  float inv = 1.f/qs;
  int q0 = __float2int_rn(w[0]*inv), q1 = __float2int_rn(w[1]*inv);
  int q2 = __float2int_rn(w[2]*inv), q3 = __float2int_rn(w[3]*inv);
  q0 = min(127,max(-127,q0)); q1 = min(127,max(-127,q1));
  q2 = min(127,max(-127,q2)); q3 = min(127,max(-127,q3));
  u32 pk = (u32)(q0&0xff) | ((u32)(q1&0xff)<<8) | ((u32)(q2&0xff)<<16) | ((u32)(q3&0xff)<<24);
  *(u32*)&WsQ[(size_t)j*512 + blk*64 + fr*4] = pk;
  if(t==0) wscale[j] = qs*(1.f/127.f);
}

// ---------------------------------------------------------------- reservoir scan: SINGLE workgroup
// 1024 threads = 16 waves (4 waves/SIMD), r8/r10 barrier skeleton. Each lane owns
// (batch fq, 2 pi-contiguous cols). HsB history store deferred to next iteration's top.
// Ws register/AGPR-resident i8 MFMA B-fragments (asm-pinned). 16-row zero-padded state
// tile, XOR bank-swizzle on reads, matching XOR on writes.
__global__ __launch_bounds__(1024) void scan_kernel(
  const signed char* __restrict__ WsQ, const float* __restrict__ wscale,
  const float* __restrict__ u, const float* __restrict__ leak_p,
  u16* __restrict__ HsB)
{
  const int t = threadIdx.x;
  const int w = t>>6, lane = t&63, fr = lane&15, fq = lane>>4;
  const float lk = sigm(leak_p[0]);
  const float omlk = 1.f - lk;
  __shared__ signed char Sl[2][16*512];        // [parity][16 rows][512] i8; rows !=4b stay 0
  for(int i=t; i<4096; i+=1024) ((u32*)Sl)[i] = 0u;
  // lane owns batch fq, pi-positions pc = w*32 + fr*2 + {0,1}
  const int pbase = w*32 + fr*2;
  float mysc[2];
  i32x4 bw[2][8];
  #pragma unroll
  for(int cg=0; cg<2; ++cg){
    int pc = pbase + cg;
    int oc = (pc & ~63) | ((pc&3)<<4) | ((pc>>2)&15);   // inverse-pi: orig col
    mysc[cg] = wscale[oc];
    #pragma unroll
    for(int ks=0; ks<8; ++ks)
      bw[cg][ks] = *(const i32x4*)&WsQ[(size_t)oc*512 + ks*64 + fq*16];
  }
  #pragma unroll
  for(int cg=0; cg<2; ++cg)
    #pragma unroll
    for(int ks=0; ks<8; ++ks)
      asm volatile("" : "+v"(bw[cg][ks]));
  float hp0 = 0.f, hp1 = 0.f;
  const float* up = u + (size_t)(fq*1024)*512 + pbase;   // pi-ordered u
  u16* hsp = HsB + (size_t)(fq*1024)*512 + pbase;        // pi-ordered Hs
  float2 uvc = *(const float2*)up;  up += 512;
  const int rdswz = ((fr&3)<<4) ^ (((fr>>2)&3)<<6);   // read-side bank swizzle for row fr
  const int woff = (4*fq)*512 + (pbase ^ (fq<<6));    // write slot (row 4fq), b16
  u32 p01v = 0u;                                      // deferred history word
  __syncthreads();
  for(int ts=0; ts<1024; ++ts){
    float2 uvn = *(const float2*)up;  up += 512;
    if(ts > 0){ *(u32*)hsp = p01v;  hsp += 512; }
    const signed char* Sb = Sl[ts&1];
    i32x4 accA[2], accB[2];
    { i32x4 z = {0,0,0,0}; accA[0]=z; accA[1]=z; accB[0]=z; accB[1]=z; }
    {
      i32x4 af[4];
      #pragma unroll
      for(int ks=0; ks<4; ++ks)
        af[ks] = *(const i32x4*)&Sb[fr*512 + ((ks*64 + fq*16) ^ rdswz)];
      #pragma unroll
      for(int ks=0; ks<4; ++ks){
        accA[0] = __builtin_amdgcn_mfma_i32_16x16x64_i8(af[ks], bw[0][ks], accA[0], 0,0,0);
        accA[1] = __builtin_amdgcn_mfma_i32_16x16x64_i8(af[ks], bw[1][ks], accA[1], 0,0,0);
      }
    }
    {
      i32x4 af[4];
      #pragma unroll
      for(int ks=0; ks<4; ++ks)
        af[ks] = *(const i32x4*)&Sb[fr*512 + (((ks+4)*64 + fq*16) ^ rdswz)];
      #pragma unroll
      for(int ks=0; ks<4; ++ks){
        accB[0] = __builtin_amdgcn_mfma_i32_16x16x64_i8(af[ks], bw[0][ks+4], accB[0], 0,0,0);
        accB[1] = __builtin_amdgcn_mfma_i32_16x16x64_i8(af[ks], bw[1][ks+4], accB[1], 0,0,0);
      }
    }
    float pre0 = (float)(accA[0][0] + accB[0][0])*mysc[0] + uvc.x;
    float pre1 = (float)(accA[1][0] + accB[1][0])*mysc[1] + uvc.y;
    float h0 = omlk*hp0 + lk*tanh_fast(pre0);
    float h1 = omlk*hp1 + lk*tanh_fast(pre1);
    hp0 = h0; hp1 = h1;
    int q0 = __float2int_rn(h0*127.f), q1 = __float2int_rn(h1*127.f);
    u16 qp = (u16)((q0&0xff) | ((q1&0xff)<<8));
    *(u16*)&Sl[(ts+1)&1][woff] = qp;
    asm volatile("v_cvt_pk_bf16_f32 %0, %1, %2" : "=v"(p01v) : "v"(h0), "v"(h1));
    uvc = uvn;
    asm volatile("s_waitcnt lgkmcnt(0)" ::: "memory");
    __builtin_amdgcn_s_barrier();
    asm volatile("" ::: "memory");
  }
  *(u32*)hsp = p01v;   // final step's history
}

// ---------------------------------------------------------------- memory attention (M=64 keys)
__global__ __launch_bounds__(256) void mem_kernel(
  const u16* __restrict__ qb, const u16* __restrict__ keysB, const u16* __restrict__ valsB,
  u16* __restrict__ ctx2b)
{
  const int t = threadIdx.x, rt = blockIdx.x;
  const int wid = t>>6, lane = t&63, fr = lane&15, fq = lane>>4;
  __shared__ float S[64][65];
  __shared__ u16 Pl[64][72];
  __shared__ u16 VT[256][72];
  {
    f32x4 accs[4] = {};
    for(int ks=0; ks<16; ++ks){
      bf16x8 bfrag = *(const bf16x8*)&keysB[(size_t)(wid*16+fr)*512 + ks*32 + fq*8];
      #pragma unroll
      for(int mt=0;mt<4;++mt){
        bf16x8 afrag = *(const bf16x8*)&qb[(size_t)(rt*64+mt*16+fr)*512 + ks*32 + fq*8];
        accs[mt] = __builtin_amdgcn_mfma_f32_16x16x32_bf16(afrag, bfrag, accs[mt], 0,0,0);
      }
    }
    #pragma unroll
    for(int mt=0;mt<4;++mt)
      #pragma unroll
      for(int i=0;i<4;++i)
        S[mt*16+fq*4+i][wid*16+fr] = accs[mt][i];
  }
  __syncthreads();
  if(t<64){
    float m = -1e30f;
    for(int j=0;j<64;++j) m = fmaxf(m, S[t][j]);
    const float scale = 0.04419417382f; // 1/sqrt(512)
    float sum = 0.f;
    for(int j=0;j<64;++j){ float p = __expf((S[t][j]-m)*scale); sum += p; S[t][j] = p; }
    float inv = 1.f/sum;
    for(int j=0;j<64;++j) Pl[t][j] = f2bf(S[t][j]*inv);
  }
  __syncthreads();
  for(int pass=0; pass<2; ++pass){
    {
      int k = t&63, cb = t>>6;
      #pragma unroll
      for(int i=0;i<8;++i){
        int d0 = (cb + i*4)*8;
        uint4 v = *(const uint4*)&valsB[(size_t)k*512 + pass*256 + d0];
        VT[d0+0][k]=(u16)(v.x); VT[d0+1][k]=(u16)(v.x>>16);
        VT[d0+2][k]=(u16)(v.y); VT[d0+3][k]=(u16)(v.y>>16);
        VT[d0+4][k]=(u16)(v.z); VT[d0+5][k]=(u16)(v.z>>16);
        VT[d0+6][k]=(u16)(v.w); VT[d0+7][k]=(u16)(v.w>>16);
      }
    }
    __syncthreads();
    f32x4 accp[4][4] = {};
    #pragma unroll
    for(int kk=0;kk<2;++kk){
      bf16x8 af[4], bf[4];
      #pragma unroll
      for(int mt=0;mt<4;++mt) af[mt] = *(const bf16x8*)&Pl[mt*16+fr][kk*32+fq*8];
      #pragma unroll
      for(int nt=0;nt<4;++nt) bf[nt] = *(const bf16x8*)&VT[wid*64+nt*16+fr][kk*32+fq*8];
      #pragma unroll
      for(int mt=0;mt<4;++mt)
        #pragma unroll
        for(int nt=0;nt<4;++nt)
          accp[mt][nt] = __builtin_amdgcn_mfma_f32_16x16x32_bf16(af[mt], bf[nt], accp[mt][nt], 0,0,0);
    }
    #pragma unroll
    for(int mt=0;mt<4;++mt)
      #pragma unroll
      for(int nt=0;nt<4;++nt){
        int row = rt*64 + mt*16 + fq*4;
        int col = pass*256 + wid*64 + nt*16 + fr;
        #pragma unroll
        for(int i=0;i<4;++i)
          ctx2b[(size_t)(row+i)*512 + col] = f2bf(accp[mt][nt][i]);
      }
    __syncthreads();
  }
}

// ---------------------------------------------------------------- ffn prod*gate -> bf16
__global__ __launch_bounds__(256) void prodgate(const float* __restrict__ ri, const float* __restrict__ g,
                         u16* __restrict__ pgb)
{
  int gi = blockIdx.x*256 + threadIdx.x;
  int row = gi>>7, c4 = (gi&127)*4;
  const float* base = ri + (size_t)row*512;
  float4 gv = *(const float4*)&g[(size_t)row*512 + c4];
  float4 o;
  if(c4 < 256){
    float4 r = *(const float4*)&base[c4];
    float4 ii = *(const float4*)&base[256+c4];
    o.x = (r.x*r.x - ii.x*ii.x)*gv.x; o.y = (r.y*r.y - ii.y*ii.y)*gv.y;
    o.z = (r.z*r.z - ii.z*ii.z)*gv.z; o.w = (r.w*r.w - ii.w*ii.w)*gv.w;
  } else {
    float4 r = *(const float4*)&base[c4-256];
    float4 ii = *(const float4*)&base[c4];
    o.x = 2.f*r.x*ii.x*gv.x; o.y = 2.f*r.y*ii.y*gv.y;
    o.z = 2.f*r.z*ii.z*gv.z; o.w = 2.f*r.w*ii.w*gv.w;
  }
  ushort4 us; us.x=f2bf(o.x); us.y=f2bf(o.y); us.z=f2bf(o.z); us.w=f2bf(o.w);
  *(ushort4*)&pgb[(size_t)row*512 + c4] = us;
}

// ================================================================ host
static void launch_gemm(int epi, dim3 grid, const u16* A, const u16* B, int K, int ldc,
  float* outf, u16* outb, const float* bias, const float* resid, const float* aux,
  float* outf2, const float* scal, int ad, hipStream_t s)
{
  switch(epi){
    case 0: gemm_nt<0><<<grid,256,0,s>>>(A,B,K,ldc,outf,outb,bias,resid,aux,outf2,scal,ad); break;
    case 1: gemm_nt<1><<<grid,256,0,s>>>(A,B,K,ldc,outf,outb,bias,resid,aux,outf2,scal,ad); break;
    case 4: gemm_nt<4><<<grid,256,0,s>>>(A,B,K,ldc,outf,outb,bias,resid,aux,outf2,scal,ad); break;
    case 5: gemm_nt<5><<<grid,256,0,s>>>(A,B,K,ldc,outf,outb,bias,resid,aux,outf2,scal,ad); break;
    case 6: gemm_nt<6><<<grid,256,0,s>>>(A,B,K,ldc,outf,outb,bias,resid,aux,outf2,scal,ad); break;
    case 8: gemm_nt<8><<<grid,256,0,s>>>(A,B,K,ldc,outf,outb,bias,resid,aux,outf2,scal,ad); break;
    case 9: gemm_nt<9><<<grid,256,0,s>>>(A,B,K,ldc,outf,outb,bias,resid,aux,outf2,scal,ad); break;
    case 10: gemm_nt<10><<<grid,256,0,s>>>(A,B,K,ldc,outf,outb,bias,resid,aux,outf2,scal,ad); break;
    case 11: gemm_nt<11><<<grid,256,0,s>>>(A,B,K,ldc,outf,outb,bias,resid,aux,outf2,scal,ad); break;
    case 12: gemm_nt<12><<<grid,256,0,s>>>(A,B,K,ldc,outf,outb,bias,resid,aux,outf2,scal,ad); break;
  }
}

extern "C" void kernel_launch(void* const* d_in, const int* in_sizes, int n_in,
                              void* d_out, int out_size, void* d_ws, size_t ws_size,
                              hipStream_t stream)
{
  const float* x      = (const float*)d_in[0];
  const float* ln1g   = (const float*)d_in[1];  const float* ln1b = (const float*)d_in[2];
  const float* ln2g   = (const float*)d_in[3];  const float* ln2b = (const float*)d_in[4];
  const float* ln3g   = (const float*)d_in[5];  const float* ln3b = (const float*)d_in[6];
  const float* ln4g   = (const float*)d_in[7];  const float* ln4b = (const float*)d_in[8];
  const float* aWp    = (const float*)d_in[9];  const float* abp  = (const float*)d_in[10];
  const float* aWv    = (const float*)d_in[11]; const float* aWo  = (const float*)d_in[12];
  const float* fWr    = (const float*)d_in[13]; const float* fbr  = (const float*)d_in[14];
  const float* fWi    = (const float*)d_in[15]; const float* fbi  = (const float*)d_in[16];
  const float* fWg    = (const float*)d_in[17]; const float* fbg  = (const float*)d_in[18];
  const float* fWo    = (const float*)d_in[19]; const float* fbo  = (const float*)d_in[20];
  const float* rWin   = (const float*)d_in[21]; const float* rWres= (const float*)d_in[22];
  const float* rlogr  = (const float*)d_in[23]; const float* rleak= (const float*)d_in[24];
  const float* rread  = (const float*)d_in[25]; const float* rv0  = (const float*)d_in[26];
  const float* mkeys  = (const float*)d_in[27]; const float* mvals= (const float*)d_in[28];
  const float* mWq    = (const float*)d_in[29]; const float* mWo  = (const float*)d_in[30];
  const float* mbo    = (const float*)d_in[31];
  const float* sRw    = (const float*)d_in[32]; const float* sRb  = (const float*)d_in[33];
  const float* salpha = (const float*)d_in[34];
  (void)in_sizes; (void)n_in; (void)out_size;

  char* ws = (char*)d_ws;
  float* XCUR  = (float*)(ws + 0);               // x1..x3 running residual
  u16*   X4B   = (u16*)  (ws + 8388608);         // bf16 x4 (HB region; HB dead by then)
  u16*   HB    = (u16*)  (ws + 8388608);         // ln outputs
  float* VU    = (float*)(ws + 12582912);        // V / u(pi) / ri
  u16*   TBUF  = (u16*)  (ws + 12582912);        // sheaf T [4096][2048] bf16 = 16MB
                                                 //   (VU/PATHS/CTXB/HSB all dead at sheaf)
  float* PATHS = (float*)(ws + 20971520);
  u16*   CTXB  = (u16*)  (ws + 23068672);        // ctx / qb / pgb
  u16*   HSB   = (u16*)  (ws + 27262976);        // Hs(pi cols) / ctx2b
  char* WB = ws + 31457280;
  u16* WpB   = (u16*)(WB + 0);                   // 128 rows } contiguous 640-row block
  u16* WvB   = (u16*)(WB + 131072);              // 512 rows }
  u16* WoB   = (u16*)(WB + 655360);
  u16* WinB  = (u16*)(WB + 1179648);
  u16* rdB   = (u16*)(WB + 1703936);             // K in pi-order
  u16* WqB   = (u16*)(WB + 2228224);
  u16* keysB = (u16*)(WB + 2752512);
  u16* valsB = (u16*)(WB + 2818048);
  u16* mWoB  = (u16*)(WB + 2883584);
  u16* WrB   = (u16*)(WB + 3407872);             // 256 rows } contiguous 1024-row block
  u16* WiB   = (u16*)(WB + 3670016);             // 256 rows }
  u16* WgB   = (u16*)(WB + 3932160);             // 512 rows }
  u16* fWoB  = (u16*)(WB + 4456448);
  u16* RwB   = (u16*)(WB + 4980736);             // 2048 rows contiguous (sheaf-1 fused B)
  u16* RwTB  = (u16*)(WB + 7077888);             // RwT' [512][2048] (sheaf-2 fused B)
  signed char* WsQ = (signed char*)(WB + 9175040); // 512x512 i8, K pi-order
  float* wscale = (float*)(WB + 9437184);
  float* bpp = (float*)(WB + 9699328);             // 128 f32 (padded attn path bias)
  float* bpc = (float*)(WB + 9699840);             // 1024 f32 (ffn concat bias)
  float* ssv = (float*)(WB + 9733632);
  float* vr  = (float*)(WB + 9733696);             // 4 x 512 f32
  float* GATE = (float*)d_out;                     // gate scratch, overwritten by x4 later

  if(ws_size < (size_t)41200000) return;

  prep_weights<<<6915,128,0,stream>>>(aWp,aWv,aWo,rWin,rread,mWq,mkeys,mvals,mWo,fWr,fWi,fWg,fWo,sRw,
      abp, fbr, fbi, fbg,
      WpB,WvB,WoB,WinB,rdB,WqB,keysB,valsB,mWoB,WrB,WiB,WgB,fWoB,RwB,bpp,bpc,ssv);
  transpose_rw<<<dim3(16,16,4),256,0,stream>>>(sRw, RwTB);

  dim3 g512(64,8), g640(64,10), g1024(64,16), g2048(64,32);

  // ---- attention (Wp+Wv fused)
  ln_kernel<<<1024,256,0,stream>>>(x, ln1g, ln1b, HB);
  launch_gemm(10, g640, HB, WpB, 512, 0, PATHS, nullptr, bpp, nullptr, nullptr, VU, nullptr, 0, stream);
  attn_kernel<<<dim3(16,32),128,0,stream>>>(PATHS, VU, CTXB);
  launch_gemm(1, g512, CTXB, WoB, 512, 512, XCUR, nullptr, nullptr, x, nullptr, nullptr, nullptr, 0, stream);

  // ---- reservoir (u written in pi-order via EPI11)
  ln_kernel<<<1024,256,0,stream>>>(XCUR, ln2g, ln2b, HB);
  launch_gemm(11, g512, HB, WinB, 512, 512, VU, nullptr, nullptr, nullptr, nullptr, nullptr, nullptr, 0, stream);
  pmv<<<32,256,0,stream>>>(rWres, rv0,   &ssv[0], &vr[0],    &ssv[1]);
  pmv<<<32,256,0,stream>>>(rWres, &vr[0],   &ssv[1], &vr[512],  &ssv[2]);
  pmv<<<32,256,0,stream>>>(rWres, &vr[512], &ssv[2], &vr[1024], &ssv[3]);
  pmv<<<32,256,0,stream>>>(rWres, &vr[1024],&ssv[3], &vr[1536], &ssv[4]);
  scale_ws<<<512,128,0,stream>>>(rWres, &ssv[4], rlogr, WsQ, wscale);
  scan_kernel<<<1,1024,0,stream>>>(WsQ, wscale, VU, rleak, HSB);
  launch_gemm(1, g512, HSB, rdB, 512, 512, XCUR, nullptr, nullptr, XCUR, nullptr, nullptr, nullptr, 0, stream);

  // ---- memory
  ln_kernel<<<1024,256,0,stream>>>(XCUR, ln3g, ln3b, HB);
  launch_gemm(4, g512, HB, WqB, 512, 512, nullptr, CTXB, nullptr, nullptr, nullptr, nullptr, nullptr, 0, stream);
  mem_kernel<<<64,256,0,stream>>>(CTXB, keysB, valsB, HSB);
  launch_gemm(5, g512, HSB, mWoB, 512, 512, XCUR, nullptr, mbo, XCUR, nullptr, nullptr, nullptr, 0, stream);

  // ---- ffn (Wr+Wi+Wg fused)
  ln_kernel<<<1024,256,0,stream>>>(XCUR, ln4g, ln4b, HB);
  launch_gemm(9, g1024, HB, WrB, 512, 0, VU, nullptr, bpc, nullptr, nullptr, GATE, nullptr, 0, stream);
  prodgate<<<2048,256,0,stream>>>(VU, GATE, CTXB);
  // x4 = x3 + ffn_out -> d_out (f32) + X4B (bf16, in dead HB region)
  launch_gemm(6, g512, CTXB, fWoB, 512, 512, nullptr, X4B, fbo, XCUR, nullptr, (float*)d_out, nullptr, 0, stream);

  // ---- sheaf, 2 fused GEMMs:
  // T[r][idx*512+c] = (x4@Rw_idx^T)[r][c] + Rb[idx][c] - shift_idx(x4)[r][c]   (EPI12, bf16)
  launch_gemm(12, g2048, X4B, RwB, 512, 0, nullptr, TBUF, sRb, nullptr, (const float*)X4B, nullptr, nullptr, 0, stream);
  // d_out -= |alpha| * T @ RwT'   (K=2048 contraction == sum over idx of T_idx@Rw_idx)
  launch_gemm(8, g512, TBUF, RwTB, 2048, 512, (float*)d_out, nullptr, nullptr, nullptr, nullptr, nullptr, salpha, 0, stream);
}